// Round 11
// baseline (384.939 us; speedup 1.0000x reference)
//
#include <hip/hip_runtime.h>
#include <hip/hip_bf16.h>

// Problem dims (fixed): B*N=32768, IN=256, H=256, I=64, A=64, NA=32, NH=256
#define BN_ 32768

using bf16 = __hip_bfloat16;
typedef __bf16 v8bf __attribute__((ext_vector_type(8)));
typedef unsigned short v8us __attribute__((ext_vector_type(8)));
typedef float v4f __attribute__((ext_vector_type(4)));

__device__ __forceinline__ float b2f(bf16 x) { return __bfloat162float(x); }
__device__ __forceinline__ bf16 f2b(float x) { return __float2bfloat16(x); }
__device__ __forceinline__ unsigned short f2bu(float x) {
  bf16 h = __float2bfloat16(x);
  return *reinterpret_cast<unsigned short*>(&h);
}
__device__ __forceinline__ float bu2f(unsigned short u) {
  union { unsigned int i; float f; } x;
  x.i = ((unsigned int)u) << 16;
  return x.f;
}
__device__ __forceinline__ void gl_lds16(const void* g, void* l) {
  __builtin_amdgcn_global_load_lds(
      (const __attribute__((address_space(1))) void*)g,
      (__attribute__((address_space(3))) void*)l, 16, 0, 0);
}
// Fast transcendentals: |err| ~1e-6 relative, exact at +-inf. Fine vs bf16 noise.
__device__ __forceinline__ float fsig(float x) { return 1.f / (1.f + __expf(-x)); }
__device__ __forceinline__ float ftanh(float x) {
  return 1.f - 2.f / (__expf(2.f * x) + 1.f);
}
template <int CF>
__device__ __forceinline__ void cstore(void* C, size_t off, float v) {
  if constexpr (CF) ((float*)C)[off] = v;
  else ((bf16*)C)[off] = f2b(v);
}
// XCD-aware bijective swizzle: same-A blocks adjacent on one XCD L2.
__device__ __forceinline__ int xcd_swz() {
  const int nbx = gridDim.x, nby = gridDim.y;
  const int f = blockIdx.y * nbx + blockIdx.x;
  const int nwg = nbx * nby;
  const int q = nwg >> 3, r = nwg & 7;
  const int xcd = f & 7, l = f >> 3;
  if (r == 0) return xcd * q + l;
  return (xcd < r ? xcd * (q + 1) : r * (q + 1) + (xcd - r) * q) + l;
}

// C = epilogue(Acat @ Bcat^T + bias). CF: 1 -> C fp32, 0 -> C bf16.
// Acat: cols [0,KS) from A1, [KS,K) from A2 (KS=0 -> A1 only). A1M/A2M: 1=fp32, 0=bf16.
// ATF: 1 -> A1 is bf16 and gets v=leaky(v*tsc[col]+tsh[col]) applied during staging.
// ACT: 0 none, 1 relu, 5 intent epilogue (requires TN=128, WC=1, FM=1: thread holds
//      mean col j and logstd col j+4; writes C=out_ie fp32, pit=intent fp32,
//      pitb bf16 DENSE stride 64).
// STATS: 1 -> emit per-column partial sum/sumsq (requires TM=64, WR=2:
//   slot = (gcol<<10) + (bm>>6)*2 + rowwave; sums at PART[slot], sumsq at +262144).
// QKV: 1 -> route stores: gcol<128 -> C (ldc=128 bf16), else C2 (ldc=64 bf16).
template <int TM, int TN, int WR, int WC, int ACT, int A1M, int A2M, int KS, int KSB,
          int CF, int ATF, int STATS, int QKV>
__global__ __launch_bounds__(256) void gemm_bt(
    const void* __restrict__ A1, int lda1, const void* __restrict__ A2, int lda2,
    const bf16* __restrict__ B1, const bf16* __restrict__ B2, int ldb,
    const float* __restrict__ bias, void* C, int ldc, int K,
    const float* __restrict__ tsc, const float* __restrict__ tsh,
    float* __restrict__ PART, const float* __restrict__ pe,
    float* __restrict__ pit, unsigned short* __restrict__ pitb, void* C2) {
  constexpr int BK = 64;
  __shared__ __align__(16) unsigned short As[TM * BK];
  __shared__ __align__(16) unsigned short Bs[TN * BK];
  const int tid = threadIdx.x;
  const int wv = tid >> 6;
  const int lane = tid & 63;
  const int w = xcd_swz();
  const int bm = (w / gridDim.y) * TM;
  const int bn = (w % gridDim.y) * TN;

  constexpr int WM = TM / WR, WN = TN / WC;
  constexpr int FM = WM / 16, FN = WN / 16;
  const int wm0 = (wv % WR) * WM;
  const int wn0 = (wv / WR) * WN;

  v4f acc[FM][FN];
  const v4f vzero = {0.f, 0.f, 0.f, 0.f};
  for (int i = 0; i < FM; ++i)
    for (int j = 0; j < FN; ++j) acc[i][j] = vzero;

  const int lrow = lane >> 3;       // row within 8-row chunk
  const int lcol = (lane & 7) * 8;  // col offset, 8 elems per lane
  const int mr = lane & 15;         // MFMA m/n index
  const int kq = (lane >> 4) * 8;   // MFMA k offset

  for (int k0 = 0; k0 < K; k0 += BK) {
    {  // ---- stage A tile ----
      const bool useA1 = (KS == 0) || (k0 < KS);
      const void* Ap = useA1 ? A1 : A2;
      const int lda = useA1 ? lda1 : lda2;
      const int ka = useA1 ? k0 : k0 - KS;
      const bool f32 = useA1 ? (A1M == 1) : (A2M == 1);
      if (ATF && useA1) {
        // bf16 in + per-column BN affine + leaky relu, register-staged
        const unsigned short* Ab = (const unsigned short*)Ap;
        const float4 s0 = *(const float4*)(tsc + ka + lcol);
        const float4 s1 = *(const float4*)(tsc + ka + lcol + 4);
        const float4 h0 = *(const float4*)(tsh + ka + lcol);
        const float4 h1 = *(const float4*)(tsh + ka + lcol + 4);
        const float sc[8] = {s0.x, s0.y, s0.z, s0.w, s1.x, s1.y, s1.z, s1.w};
        const float sh[8] = {h0.x, h0.y, h0.z, h0.w, h1.x, h1.y, h1.z, h1.w};
        for (int ch = wv; ch < TM / 8; ch += 4) {
          const unsigned short* s = Ab + (size_t)(bm + ch * 8 + lrow) * lda + ka + lcol;
          v8us zin = *(const v8us*)s;
          v8us d;
#pragma unroll
          for (int u = 0; u < 8; ++u) {
            float v = bu2f(zin[u]) * sc[u] + sh[u];
            d[u] = f2bu(v > 0.f ? v : 0.01f * v);
          }
          *(v8us*)(As + ch * 8 * BK + lane * 8) = d;
        }
      } else if (f32) {
        const float* Af = (const float*)Ap;
        for (int ch = wv; ch < TM / 8; ch += 4) {
          const float* s = Af + (size_t)(bm + ch * 8 + lrow) * lda + ka + lcol;
          float4 x0 = *(const float4*)s;
          float4 x1 = *(const float4*)(s + 4);
          v8us d;
          d[0]=f2bu(x0.x); d[1]=f2bu(x0.y); d[2]=f2bu(x0.z); d[3]=f2bu(x0.w);
          d[4]=f2bu(x1.x); d[5]=f2bu(x1.y); d[6]=f2bu(x1.z); d[7]=f2bu(x1.w);
          *(v8us*)(As + ch * 8 * BK + lane * 8) = d;
        }
      } else {
        const unsigned short* Ab = (const unsigned short*)Ap;
        for (int ch = wv; ch < TM / 8; ch += 4)
          gl_lds16(Ab + (size_t)(bm + ch * 8 + lrow) * lda + ka + lcol,
                   As + ch * 8 * BK);
      }
    }
    {  // ---- stage B tile (canonical bf16) ----
      const bool useB1 = (KSB == 0) || (k0 < KSB);
      const bf16* Bp = useB1 ? B1 : B2;
      const int kb = useB1 ? k0 : k0 - KSB;
      for (int ch = wv; ch < TN / 8; ch += 4)
        gl_lds16((const unsigned short*)Bp + (size_t)(bn + ch * 8 + lrow) * ldb + kb + lcol,
                 Bs + ch * 8 * BK);
    }
    __syncthreads();
#pragma unroll
    for (int kk = 0; kk < BK; kk += 32) {
      v8bf af[FM], bfr[FN];
#pragma unroll
      for (int i = 0; i < FM; ++i)
        af[i] = *(const v8bf*)(As + (wm0 + i * 16 + mr) * BK + kk + kq);
#pragma unroll
      for (int j = 0; j < FN; ++j)
        bfr[j] = *(const v8bf*)(Bs + (wn0 + j * 16 + mr) * BK + kk + kq);
#pragma unroll
      for (int i = 0; i < FM; ++i)
#pragma unroll
        for (int j = 0; j < FN; ++j)
          acc[i][j] = __builtin_amdgcn_mfma_f32_16x16x32_bf16(af[i], bfr[j],
                                                              acc[i][j], 0, 0, 0);
    }
    __syncthreads();
  }
  const int crow = (lane >> 4) * 4;

  if constexpr (ACT == 5) {
    // intent epilogue: TN=128, WC=1 -> wn0=0, FN=8, FM=1. Thread holds mean col
    // (j<4, cols 0..63) and logstd col (j+4, cols 64..127) in its own acc.
#pragma unroll
    for (int j = 0; j < 4; ++j) {
      const int gcol = bn + j * 16 + mr;  // 0..63
      const float bmn = bias[gcol];
      const float bsd = bias[gcol + 64];
#pragma unroll
      for (int r = 0; r < 4; ++r) {
        const int grow = bm + wm0 + crow + r;
        const float mean = acc[0][j][r] + bmn;
        const float lstd = acc[0][j + 4][r] + bsd;
        ((float*)C)[(size_t)grow * 128 + gcol] = mean;
        ((float*)C)[(size_t)grow * 128 + gcol + 64] = lstd;
        const float sd = fmaxf(__expf(lstd), 0.002f);
        const float iv = mean + pe[(size_t)grow * 64 + gcol] * sd;
        pit[(size_t)grow * 64 + gcol] = iv;
        pitb[(size_t)grow * 64 + gcol] = f2bu(iv);
      }
    }
  } else {
#pragma unroll
    for (int j = 0; j < FN; ++j) {
      const int gcol = bn + wn0 + j * 16 + mr;
      const float bv = bias[gcol];
      float ps = 0.f, pq = 0.f;
#pragma unroll
      for (int i = 0; i < FM; ++i) {
#pragma unroll
        for (int r = 0; r < 4; ++r) {
          const int grow = bm + wm0 + i * 16 + crow + r;
          float v = acc[i][j][r] + bv;
          if (ACT == 1) v = v > 0.f ? v : 0.f;
          if constexpr (QKV) {
            if (gcol < 128) ((bf16*)C)[(size_t)grow * 128 + gcol] = f2b(v);
            else ((bf16*)C2)[(size_t)grow * 64 + (gcol - 128)] = f2b(v);
          } else if constexpr (STATS) {
            const unsigned short d = f2bu(v);
            ((bf16*)C)[(size_t)grow * ldc + gcol] = *(const bf16*)&d;
            const float vr = bu2f(d);
            ps += vr; pq += vr * vr;
          } else {
            cstore<CF>(C, (size_t)grow * ldc + gcol, v);
          }
        }
      }
      if constexpr (STATS) {
        // reduce across the 4 row-quarter lanes (same mr, lane>>4 = 0..3)
        ps += __shfl_xor(ps, 16); ps += __shfl_xor(ps, 32);
        pq += __shfl_xor(pq, 16); pq += __shfl_xor(pq, 32);
        if (lane < 16) {
          const int slot = (gcol << 10) + ((bm >> 6) << 1) + (wv % WR);
          PART[slot] = ps;
          PART[262144 + slot] = pq;
        }
      }
    }
  }
}

// Reduce PART -> BN scale/shift. One block per column, 64 lanes, coalesced float4.
// 1024 slots per column (512 m-blocks x 2 row-waves at TM=64).
__global__ __launch_bounds__(64) void bn_finalize2(
    const float* __restrict__ PART, const float* __restrict__ g,
    const float* __restrict__ b, float* __restrict__ stats) {
  const int col = blockIdx.x;
  const int lane = threadIdx.x;
  const float4* ps = (const float4*)(PART + (col << 10));
  const float4* pq = (const float4*)(PART + 262144 + (col << 10));
  float s = 0.f, q = 0.f;
#pragma unroll
  for (int u = 0; u < 4; ++u) {
    const float4 a = ps[lane * 4 + u];
    const float4 c = pq[lane * 4 + u];
    s += a.x + a.y + a.z + a.w;
    q += c.x + c.y + c.z + c.w;
  }
#pragma unroll
  for (int m = 1; m < 64; m <<= 1) {
    s += __shfl_xor(s, m);
    q += __shfl_xor(q, m);
  }
  if (lane == 0) {
    const float mean = s * (1.f / 32768.f);
    float var = q * (1.f / 32768.f) - mean * mean;
    var = fmaxf(var, 0.f);
    const float sc = g[col] * rsqrtf(var + 1e-5f);
    stats[512 + col] = sc;
    stats[768 + col] = b[col] - mean * sc;
  }
}

// FULL fused GRU: one kernel computes all six gate gemms
//   {xr,xz,xn} = X @ Wih[gate]^T, {hr,hz,hn} = HB @ Whh[gate]^T  (each MxK=256)
// and combines in registers: r=sig(xr+hr+br), z=sig(xz+hz+bz),
// n=tanh(xn+bin + r*(hn+bhn)), h=(1-z)*n + z*hprev.
// No G1 intermediate at all (saves 64 MB round-trip + one dispatch).
// Block = 64 rows x 64 h-cols; grid 2048 (512 row-blocks x 4 col-blocks),
// XCD-swizzled so the 4 col-blocks sharing A-rows are L2-adjacent.
// 4 waves in 2x2; per wave 6 x 2x2 acc fragments (96 VGPR).
// LDS: 8 staged tiles (X, HB, 3x Wih, 3x Whh) x 8 KB = 64 KB -> 2 blocks/CU.
// Epilogue: hprev batched-prefetch (L3-warm), combine, Ep-LDS transpose (pad 68),
// coalesced fp32 Hout + bf16 HB2 writes.
__global__ __launch_bounds__(256) void gru_full(
    const bf16* __restrict__ X, const bf16* __restrict__ HB,
    const bf16* __restrict__ Wih, const bf16* __restrict__ Whh,  // [768][256]
    const float* __restrict__ FBp, unsigned short* __restrict__ HB2,
    float* __restrict__ Hout) {
  constexpr int BK = 64;
  __shared__ __align__(16) unsigned short smem[32768];  // 64 KB
  float* Ein = (float*)smem;  // 64*68 fp32 (17408 B), used after the K-loop

  const int tid = threadIdx.x;
  const int wv = tid >> 6;
  const int lane = tid & 63;
  const int w = xcd_swz();
  const int bm = (w >> 2) * 64;   // row-block
  const int cb = w & 3;           // 64-col block of h
  const int wm0 = (wv & 1) * 32;
  const int wn0 = (wv >> 1) * 32;

  v4f ax_[3][2][2], ah_[3][2][2];  // [gate][i][j]
  const v4f vzero = {0.f, 0.f, 0.f, 0.f};
#pragma unroll
  for (int m = 0; m < 3; ++m)
#pragma unroll
    for (int i = 0; i < 2; ++i)
#pragma unroll
      for (int j = 0; j < 2; ++j) { ax_[m][i][j] = vzero; ah_[m][i][j] = vzero; }

  const int lrow = lane >> 3;
  const int lcol = (lane & 7) * 8;
  const int mr = lane & 15;
  const int kq = (lane >> 4) * 8;

  for (int k0 = 0; k0 < 256; k0 += BK) {
    // 8 tiles x 8 chunks(8 rows) = 64 staging jobs, split across 4 waves.
    for (int job = wv; job < 64; job += 4) {
      const int t = job >> 3, c = job & 7;
      const int row8 = c * 8 + lrow;
      const unsigned short* src;
      if (t == 0)
        src = (const unsigned short*)X + (size_t)(bm + row8) * 256 + k0 + lcol;
      else if (t == 1)
        src = (const unsigned short*)HB + (size_t)(bm + row8) * 256 + k0 + lcol;
      else if (t < 5)
        src = (const unsigned short*)Wih +
              (size_t)((t - 2) * 256 + cb * 64 + row8) * 256 + k0 + lcol;
      else
        src = (const unsigned short*)Whh +
              (size_t)((t - 5) * 256 + cb * 64 + row8) * 256 + k0 + lcol;
      gl_lds16(src, smem + t * 4096 + c * 512);
    }
    __syncthreads();
#pragma unroll
    for (int kk = 0; kk < BK; kk += 32) {
      v8bf a0[2], a1[2];
#pragma unroll
      for (int i = 0; i < 2; ++i) {
        a0[i] = *(const v8bf*)(smem + (wm0 + i * 16 + mr) * 64 + kk + kq);
        a1[i] = *(const v8bf*)(smem + 4096 + (wm0 + i * 16 + mr) * 64 + kk + kq);
      }
#pragma unroll
      for (int m = 0; m < 3; ++m) {
        v8bf b0[2], b1[2];
#pragma unroll
        for (int j = 0; j < 2; ++j) {
          b0[j] = *(const v8bf*)(smem + (2 + m) * 4096 + (wn0 + j * 16 + mr) * 64 + kk + kq);
          b1[j] = *(const v8bf*)(smem + (5 + m) * 4096 + (wn0 + j * 16 + mr) * 64 + kk + kq);
        }
#pragma unroll
        for (int i = 0; i < 2; ++i)
#pragma unroll
          for (int j = 0; j < 2; ++j) {
            ax_[m][i][j] = __builtin_amdgcn_mfma_f32_16x16x32_bf16(
                a0[i], b0[j], ax_[m][i][j], 0, 0, 0);
            ah_[m][i][j] = __builtin_amdgcn_mfma_f32_16x16x32_bf16(
                a1[i], b1[j], ah_[m][i][j], 0, 0, 0);
          }
      }
    }
    __syncthreads();
  }

  const int crow = (lane >> 4) * 4;
  // ---- batched hprev prefetch (16 bf16 loads, quarter-wave reads 32B spans) ----
  unsigned short hp[2][2][4];
#pragma unroll
  for (int i = 0; i < 2; ++i)
#pragma unroll
    for (int j = 0; j < 2; ++j)
#pragma unroll
      for (int r = 0; r < 4; ++r)
        hp[i][j][r] = ((const unsigned short*)HB)
            [(size_t)(bm + wm0 + i * 16 + crow + r) * 256 + cb * 64 + wn0 + j * 16 + mr];
  // ---- in-register GRU combine -> Ein (all 4 waves own disjoint quarters) ----
#pragma unroll
  for (int j = 0; j < 2; ++j) {
    const int gc = cb * 64 + wn0 + j * 16 + mr;
    const float br = FBp[256 + gc];
    const float bz = FBp[512 + gc];
    const float bin = FBp[768 + gc];
    const float bhn = FBp[1024 + gc];
#pragma unroll
    for (int i = 0; i < 2; ++i)
#pragma unroll
      for (int r = 0; r < 4; ++r) {
        const float rr = fsig(ax_[0][i][j][r] + ah_[0][i][j][r] + br);
        const float zz = fsig(ax_[1][i][j][r] + ah_[1][i][j][r] + bz);
        const float nn = ftanh(ax_[2][i][j][r] + bin + rr * (ah_[2][i][j][r] + bhn));
        const float hv = (1.f - zz) * nn + zz * bu2f(hp[i][j][r]);
        Ein[(wm0 + i * 16 + crow + r) * 68 + wn0 + j * 16 + mr] = hv;
      }
  }
  __syncthreads();
  // ---- coalesced output: thread t -> row t>>2, 16-col quarter (t&3) ----
  {
    const int orow = tid >> 2;
    const int oq = (tid & 3) * 16;
    float tmp[16];
#pragma unroll
    for (int u = 0; u < 4; ++u) {
      const float4 f = *(const float4*)(Ein + orow * 68 + oq + u * 4);
      tmp[u * 4 + 0] = f.x; tmp[u * 4 + 1] = f.y;
      tmp[u * 4 + 2] = f.z; tmp[u * 4 + 3] = f.w;
    }
    float* ho = Hout + (size_t)(bm + orow) * 256 + cb * 64 + oq;
#pragma unroll
    for (int u = 0; u < 4; ++u)
      ((float4*)ho)[u] = make_float4(tmp[u * 4], tmp[u * 4 + 1], tmp[u * 4 + 2],
                                     tmp[u * 4 + 3]);
    v8us hb0, hb1;
#pragma unroll
    for (int u = 0; u < 8; ++u) { hb0[u] = f2bu(tmp[u]); hb1[u] = f2bu(tmp[8 + u]); }
    unsigned short* hbo = HB2 + (size_t)(bm + orow) * 256 + cb * 64 + oq;
    *(v8us*)hbo = hb0;
    *(v8us*)(hbo + 8) = hb1;
  }
}

// Canonicalize (fp32 in): weights -> bf16 blob WF, biases -> fp32 blob FB; zero BN stats.
// WF element map: fc1_w@0[65536] w_ih@65536[196608] w_hh@262144[196608]
//   W1P@458752[81920 (256x320, in1_w padded 288->320)] in2_w@540672[32768]
//   (legacy gap 573440..602112 zeroed) fc2_w@602112[10240]
//   WQKV@612352[61440 = 192x320: rows 0..127 = [wq;wk] cols<64 else 0;
//   rows 128..191 = wv]
// FB float map: fc1_b@0[256] BRZ@256[512] BIN@768[256] BHN@1024[256]
//   in1_b@1280[256] in2_b@1536[128] BQK@1664[128] wv_b@1792[64] fc2_b@1856[32]
//   bn_g@1888[256] bn_b@2144[256] (gap) stats@2560[1024, zeroed]
__global__ void conv_all(
    const float* fc1_w, const float* w_ih, const float* w_hh, const float* in1_w,
    const float* in2_w, const float* wq_w, const float* wk_w, const float* wv_w,
    const float* fc2_w, const float* fc1_b, const float* b_ih, const float* b_hh,
    const float* in1_b, const float* in2_b, const float* wq_b, const float* wk_b,
    const float* wv_b, const float* fc2_b, const float* bn_g, const float* bn_b,
    bf16* __restrict__ WF, float* __restrict__ FB) {
  int idx = blockIdx.x * 256 + threadIdx.x;
  if (idx < 673792) {
    float v;
    if (idx < 65536) v = fc1_w[idx];
    else if (idx < 262144) v = w_ih[idx - 65536];
    else if (idx < 458752) v = w_hh[idx - 262144];
    else if (idx < 540672) {
      int j = idx - 458752, r = j / 320, c = j % 320;
      v = (c < 288) ? in1_w[r * 288 + c] : 0.f;
    } else if (idx < 573440) v = in2_w[idx - 540672];
    else if (idx < 602112) {
      v = 0.f;  // legacy region, dead
    } else if (idx < 612352) v = fc2_w[idx - 602112];
    else {  // WQKV 192x320
      int j = idx - 612352, r = j / 320, c = j % 320;
      if (r < 128) v = (c < 64) ? (r < 64 ? wq_w[r * 64 + c]
                                          : wk_w[(r - 64) * 64 + c]) : 0.f;
      else v = wv_w[(size_t)(r - 128) * 320 + c];
    }
    WF[idx] = f2b(v);
  } else if (idx < 677376) {
    int j = idx - 673792;  // 0..3583
    float v;
    if (j < 256) v = fc1_b[j];
    else if (j < 768) v = b_ih[j - 256] + b_hh[j - 256];
    else if (j < 1024) v = b_ih[512 + j - 768];
    else if (j < 1280) v = b_hh[512 + j - 1024];
    else if (j < 1536) v = in1_b[j - 1280];
    else if (j < 1664) v = in2_b[j - 1536];
    else if (j < 1792) { int c = j - 1664; v = (c < 64) ? wq_b[c] : wk_b[c - 64]; }
    else if (j < 1856) v = wv_b[j - 1792];
    else if (j < 1888) v = fc2_b[j - 1856];
    else if (j < 2144) v = bn_g[j - 1888];
    else if (j < 2400) v = bn_b[j - 2144];
    else v = 0.f;  // gap + stats region zeroed
    FB[j] = v;
  }
}

// One launch: hidden->HB (bf16), inputs->XB (bf16), last_actions->LAP ([la|0] bf16).
__global__ void pack_all(const float* __restrict__ h, bf16* __restrict__ hb,
                         const float* __restrict__ x, bf16* __restrict__ xb,
                         const float* __restrict__ la, bf16* __restrict__ lap) {
  const int bid = blockIdx.x;
  if (bid < 8192) {
    const float* s = bid < 4096 ? h : x;
    bf16* d = bid < 4096 ? hb : xb;
    const int i = (bid & 4095) * 256 + threadIdx.x;
    const float4 x0 = ((const float4*)s)[i * 2];
    const float4 x1 = ((const float4*)s)[i * 2 + 1];
    v8us o;
    o[0]=f2bu(x0.x); o[1]=f2bu(x0.y); o[2]=f2bu(x0.z); o[3]=f2bu(x0.w);
    o[4]=f2bu(x1.x); o[5]=f2bu(x1.y); o[6]=f2bu(x1.z); o[7]=f2bu(x1.w);
    ((v8us*)d)[i] = o;
  } else {
    const int i = (bid - 8192) * 256 + threadIdx.x;  // < 262144 (BN_*64/8)
    const int row = i >> 3, cg = i & 7;
    v8us o;
    if (cg < 4) {
      const float4 a = *(const float4*)(la + (size_t)row * 32 + cg * 8);
      const float4 b = *(const float4*)(la + (size_t)row * 32 + cg * 8 + 4);
      o[0]=f2bu(a.x); o[1]=f2bu(a.y); o[2]=f2bu(a.z); o[3]=f2bu(a.w);
      o[4]=f2bu(b.x); o[5]=f2bu(b.y); o[6]=f2bu(b.z); o[7]=f2bu(b.w);
    } else {
      for (int u = 0; u < 8; ++u) o[u] = 0;
    }
    ((v8us*)lap)[i] = o;
  }
}

// 4 heads per block (one per wave), vectorized loads.
__global__ __launch_bounds__(256) void attn(const bf16* __restrict__ QK,
                                            const bf16* __restrict__ Vv,
                                            bf16* __restrict__ comb) {
  __shared__ float q[4][8][65], k[4][8][65], v[4][8][65];
  __shared__ float al[4][8][8];
  const int wv = threadIdx.x >> 6, t = threadIdx.x & 63;
  const int b = blockIdx.x * 4 + wv;
  const size_t rb = (size_t)b * 8;
  const unsigned short* qkb = (const unsigned short*)QK + rb * 128;
#pragma unroll
  for (int p = 0; p < 2; ++p) {
    const int e = t * 8 + p * 512;
    const int row = e >> 7, col = e & 127;
    v8us d = *(const v8us*)(qkb + row * 128 + col);
    if (col < 64) {
#pragma unroll
      for (int u = 0; u < 8; ++u) q[wv][row][col + u] = bu2f(d[u]);
    } else {
#pragma unroll
      for (int u = 0; u < 8; ++u) k[wv][row][col - 64 + u] = bu2f(d[u]);
    }
  }
  {
    const int e = t * 8;
    const int row = e >> 6, col = e & 63;
    v8us d = *(const v8us*)((const unsigned short*)Vv + rb * 64 + row * 64 + col);
#pragma unroll
    for (int u = 0; u < 8; ++u) v[wv][row][col + u] = bu2f(d[u]);
  }
  __syncthreads();
  const int i = t >> 3, j = t & 7;
  float s = 0.f;
#pragma unroll
  for (int a = 0; a < 64; ++a) s += q[wv][i][a] * k[wv][j][a];
  s *= 0.125f;
  if (i == j) s = -1e9f;
  float m = s;
  m = fmaxf(m, __shfl_xor(m, 1, 8));
  m = fmaxf(m, __shfl_xor(m, 2, 8));
  m = fmaxf(m, __shfl_xor(m, 4, 8));
  float e = __expf(s - m);
  float sum = e;
  sum += __shfl_xor(sum, 1, 8);
  sum += __shfl_xor(sum, 2, 8);
  sum += __shfl_xor(sum, 4, 8);
  al[wv][i][j] = e / sum;
  __syncthreads();
  const int a0 = (t & 7) * 8;
  v8us o8;
#pragma unroll
  for (int u = 0; u < 8; ++u) {
    float o = 0.f;
#pragma unroll
    for (int jj = 0; jj < 8; ++jj) o += al[wv][i][jj] * v[wv][jj][a0 + u];
    o8[u] = f2bu(o);
  }
  *(v8us*)((unsigned short*)comb + (rb + i) * 64 + a0) = o8;
}

extern "C" void kernel_launch(void* const* d_in, const int* in_sizes, int n_in,
                              void* d_out, int out_size, void* d_ws, size_t ws_size,
                              hipStream_t stream) {
  (void)in_sizes; (void)n_in; (void)out_size; (void)ws_size;
  const float* inputs = (const float*)d_in[0];
  const float* last_actions = (const float*)d_in[1];
  const float* hidden = (const float*)d_in[2];
  const float* eps = (const float*)d_in[3];

  // d_out is FP32 (reference output dtype)
  float* out = (float*)d_out;
  float* out_lq = out;             // 32768x32 (fc2, written LAST)
  float* out_h = out + 1048576;    // 32768x256
  float* out_it = out + 9437184;   // 32768x64
  float* out_ie = out + 11534336;  // 32768x128

  // HB = bf16(hidden), scratch in the out_ie region (last read: gru_full; in2
  // writes out_ie after).
  bf16* HB = (bf16*)(out + 11534336);  // 16 MiB as bf16 (32768x256)
  // XB = bf16(inputs), scratch in the out_h region (consumed by fc1; gru_full
  // writes out_h after fc1 completes).
  bf16* XB = (bf16*)(out + 1048576);
  // LAP lives in the out_lq region (4 MiB, written only by fc2 at the end).
  bf16* LAP = (bf16*)out_lq;
  // PART: BN-stat partials (4 MiB) in the out_it region (consumed by bn_finalize2
  // before the in2 gemm writes out_it=intent).
  float* PART = out + 9437184;

  // ---- workspace ----
  char* ws = (char*)d_ws;
  bf16* X    = (bf16*)(ws + 0);            // 16 MiB (fc1 -> gru_full)
  unsigned short* HB2 = (unsigned short*)(ws + 16777216);  // 16 MiB dense h bf16
  unsigned short* ITB = (unsigned short*)(ws + 33554432);  // 4 MiB dense intent bf16
  bf16* Z1   = (bf16*)(ws + 0);            // 16 MiB over dead X (z1 -> in2)
  bf16* QK   = (bf16*)(ws + 0);            // 8 MiB over dead Z1
  bf16* V    = (bf16*)(ws + 8388608);      // 4 MiB over dead Z1
  bf16* COMB = (bf16*)(ws + 12582912);     // 4 MiB over dead Z1
  float* FB  = (float*)(ws + 50331648);    // 3584 floats @ 48 MiB mark
  bf16*  WF  = (bf16*)(ws + 50348032);     // 673792 bf16
  float* stats = FB + 2560;

  conv_all<<<2646, 256, 0, stream>>>(
      (const float*)d_in[4], (const float*)d_in[6], (const float*)d_in[7],
      (const float*)d_in[10], (const float*)d_in[14], (const float*)d_in[16],
      (const float*)d_in[18], (const float*)d_in[20], (const float*)d_in[22],
      (const float*)d_in[5], (const float*)d_in[8], (const float*)d_in[9],
      (const float*)d_in[11], (const float*)d_in[15], (const float*)d_in[17],
      (const float*)d_in[19], (const float*)d_in[21], (const float*)d_in[23],
      (const float*)d_in[12], (const float*)d_in[13], WF, FB);

  pack_all<<<9216, 256, 0, stream>>>(hidden, HB, inputs, XB, last_actions, LAP);

  // x = relu(xb @ fc1_w^T + fc1_b)   [A bf16 -> X bf16]
  gemm_bt<64, 128, 2, 2, 1, 0, 0, 0, 0, 0, 0, 0, 0><<<dim3(512, 2), 256, 0, stream>>>(
      XB, 256, nullptr, 0, WF + 0, nullptr, 256, FB + 0, X, 256, 256,
      nullptr, nullptr, nullptr, nullptr, nullptr, nullptr, nullptr);
  // out_h (fp32) + HB2 (bf16 dense) = FULL fused GRU (all 6 gate gemms + combine)
  gru_full<<<2048, 256, 0, stream>>>(
      X, HB, WF + 65536, WF + 262144, FB, HB2, out_h);

  // z1 = [h(bf16) | la_pad(bf16)] @ W1P^T + in1_b (K=320) -> Z1 bf16 + BN partials
  gemm_bt<64, 128, 2, 2, 0, 0, 0, 256, 0, 0, 0, 1, 0><<<dim3(512, 2), 256, 0, stream>>>(
      HB2, 256, LAP, 64, WF + 458752, nullptr, 320, FB + 1280, Z1, 256, 320,
      nullptr, nullptr, PART, nullptr, nullptr, nullptr, nullptr);
  bn_finalize2<<<256, 64, 0, stream>>>(PART, FB + 1888, FB + 2144, stats);
  // intent_embed + intent + ITB in ONE gemm: leaky(bn(z1)) @ in2_w^T + in2_b,
  // epilogue computes intent = mean + eps*max(exp(lstd),2e-3)  [ACT=5, WR=4/WC=1]
  gemm_bt<64, 128, 4, 1, 5, 0, 0, 0, 0, 1, 1, 0, 0><<<dim3(512, 1), 256, 0, stream>>>(
      Z1, 256, nullptr, 0, WF + 540672, nullptr, 256, FB + 1536, out_ie, 128, 256,
      stats + 512, stats + 768, nullptr, eps, out_it, ITB, nullptr);
  // q|k|v in ONE gemm: [intent(bf16) | h(bf16)] @ [wq_pad;wk_pad;wv]^T (K=320,
  // N=192); epilogue routes cols<128 -> QK, cols>=128 -> V.
  gemm_bt<64, 192, 2, 2, 0, 0, 0, 64, 0, 0, 0, 0, 1><<<dim3(512, 1), 256, 0, stream>>>(
      ITB, 64, HB2, 256, WF + 612352, nullptr, 320, FB + 1664, QK, 128, 320,
      nullptr, nullptr, nullptr, nullptr, nullptr, nullptr, V);
  attn<<<1024, 256, 0, stream>>>(QK, V, COMB);
  // local_Q (fp32) = [h(bf16) | combined(bf16)] @ fc2^T   (K=320)
  gemm_bt<64, 32, 4, 1, 0, 0, 0, 256, 0, 1, 0, 0, 0><<<dim3(512, 1), 256, 0, stream>>>(
      HB2, 256, COMB, 64, WF + 602112, nullptr, 320, FB + 1856, out_lq, 32, 320,
      nullptr, nullptr, nullptr, nullptr, nullptr, nullptr, nullptr);
}

// Round 12
// 314.851 us; speedup vs baseline: 1.2226x; 1.2226x over previous
//
#include <hip/hip_runtime.h>
#include <hip/hip_bf16.h>

// Problem dims (fixed): B*N=32768, IN=256, H=256, I=64, A=64, NA=32, NH=256
#define BN_ 32768

using bf16 = __hip_bfloat16;
typedef __bf16 v8bf __attribute__((ext_vector_type(8)));
typedef unsigned short v8us __attribute__((ext_vector_type(8)));
typedef float v4f __attribute__((ext_vector_type(4)));

__device__ __forceinline__ float b2f(bf16 x) { return __bfloat162float(x); }
__device__ __forceinline__ bf16 f2b(float x) { return __float2bfloat16(x); }
__device__ __forceinline__ unsigned short f2bu(float x) {
  bf16 h = __float2bfloat16(x);
  return *reinterpret_cast<unsigned short*>(&h);
}
__device__ __forceinline__ float bu2f(unsigned short u) {
  union { unsigned int i; float f; } x;
  x.i = ((unsigned int)u) << 16;
  return x.f;
}
__device__ __forceinline__ void gl_lds16(const void* g, void* l) {
  __builtin_amdgcn_global_load_lds(
      (const __attribute__((address_space(1))) void*)g,
      (__attribute__((address_space(3))) void*)l, 16, 0, 0);
}
// Fast transcendentals: |err| ~1e-6 relative, exact at +-inf. Fine vs bf16 noise.
__device__ __forceinline__ float fsig(float x) { return 1.f / (1.f + __expf(-x)); }
__device__ __forceinline__ float ftanh(float x) {
  return 1.f - 2.f / (__expf(2.f * x) + 1.f);
}
template <int CF>
__device__ __forceinline__ void cstore(void* C, size_t off, float v) {
  if constexpr (CF) ((float*)C)[off] = v;
  else ((bf16*)C)[off] = f2b(v);
}
// XCD-aware bijective swizzle: same-A blocks adjacent on one XCD L2.
__device__ __forceinline__ int xcd_swz() {
  const int nbx = gridDim.x, nby = gridDim.y;
  const int f = blockIdx.y * nbx + blockIdx.x;
  const int nwg = nbx * nby;
  const int q = nwg >> 3, r = nwg & 7;
  const int xcd = f & 7, l = f >> 3;
  if (r == 0) return xcd * q + l;
  return (xcd < r ? xcd * (q + 1) : r * (q + 1) + (xcd - r) * q) + l;
}

// C = epilogue(Acat @ Bcat^T + bias). CF: 1 -> C fp32, 0 -> C bf16.
// Acat: cols [0,KS) from A1, [KS,K) from A2 (KS=0 -> A1 only). A1M/A2M: 1=fp32, 0=bf16.
// ATF: 1 -> A1 is bf16 and gets v=leaky(v*tsc[col]+tsh[col]) applied during staging.
// ACT: 0 none, 1 relu, 5 intent epilogue (requires TN=128, WC=1, FM=1: thread holds
//      mean col j and logstd col j+4; writes C=out_ie fp32, pit=intent fp32,
//      pitb bf16 stride 512).
// STATS: 1 -> emit per-column partial sum/sumsq (requires TM=64, WR=2:
//   slot = (gcol<<10) + (bm>>6)*2 + rowwave; sums at PART[slot], sumsq at +262144).
// QKV: 1 -> route stores: gcol<128 -> C (ldc=128 bf16), else C2 (ldc=64 bf16).
template <int TM, int TN, int WR, int WC, int ACT, int A1M, int A2M, int KS, int KSB,
          int CF, int ATF, int STATS, int QKV>
__global__ __launch_bounds__(256) void gemm_bt(
    const void* __restrict__ A1, int lda1, const void* __restrict__ A2, int lda2,
    const bf16* __restrict__ B1, const bf16* __restrict__ B2, int ldb,
    const float* __restrict__ bias, void* C, int ldc, int K,
    const float* __restrict__ tsc, const float* __restrict__ tsh,
    float* __restrict__ PART, const float* __restrict__ pe,
    float* __restrict__ pit, unsigned short* __restrict__ pitb, void* C2) {
  constexpr int BK = 64;
  __shared__ __align__(16) unsigned short As[TM * BK];
  __shared__ __align__(16) unsigned short Bs[TN * BK];
  const int tid = threadIdx.x;
  const int wv = tid >> 6;
  const int lane = tid & 63;
  const int w = xcd_swz();
  const int bm = (w / gridDim.y) * TM;
  const int bn = (w % gridDim.y) * TN;

  constexpr int WM = TM / WR, WN = TN / WC;
  constexpr int FM = WM / 16, FN = WN / 16;
  const int wm0 = (wv % WR) * WM;
  const int wn0 = (wv / WR) * WN;

  v4f acc[FM][FN];
  const v4f vzero = {0.f, 0.f, 0.f, 0.f};
  for (int i = 0; i < FM; ++i)
    for (int j = 0; j < FN; ++j) acc[i][j] = vzero;

  const int lrow = lane >> 3;       // row within 8-row chunk
  const int lcol = (lane & 7) * 8;  // col offset, 8 elems per lane
  const int mr = lane & 15;         // MFMA m/n index
  const int kq = (lane >> 4) * 8;   // MFMA k offset

  for (int k0 = 0; k0 < K; k0 += BK) {
    {  // ---- stage A tile ----
      const bool useA1 = (KS == 0) || (k0 < KS);
      const void* Ap = useA1 ? A1 : A2;
      const int lda = useA1 ? lda1 : lda2;
      const int ka = useA1 ? k0 : k0 - KS;
      const bool f32 = useA1 ? (A1M == 1) : (A2M == 1);
      if (ATF && useA1) {
        // bf16 in + per-column BN affine + leaky relu, register-staged
        const unsigned short* Ab = (const unsigned short*)Ap;
        const float4 s0 = *(const float4*)(tsc + ka + lcol);
        const float4 s1 = *(const float4*)(tsc + ka + lcol + 4);
        const float4 h0 = *(const float4*)(tsh + ka + lcol);
        const float4 h1 = *(const float4*)(tsh + ka + lcol + 4);
        const float sc[8] = {s0.x, s0.y, s0.z, s0.w, s1.x, s1.y, s1.z, s1.w};
        const float sh[8] = {h0.x, h0.y, h0.z, h0.w, h1.x, h1.y, h1.z, h1.w};
        for (int ch = wv; ch < TM / 8; ch += 4) {
          const unsigned short* s = Ab + (size_t)(bm + ch * 8 + lrow) * lda + ka + lcol;
          v8us zin = *(const v8us*)s;
          v8us d;
#pragma unroll
          for (int u = 0; u < 8; ++u) {
            float v = bu2f(zin[u]) * sc[u] + sh[u];
            d[u] = f2bu(v > 0.f ? v : 0.01f * v);
          }
          *(v8us*)(As + ch * 8 * BK + lane * 8) = d;
        }
      } else if (f32) {
        const float* Af = (const float*)Ap;
        for (int ch = wv; ch < TM / 8; ch += 4) {
          const float* s = Af + (size_t)(bm + ch * 8 + lrow) * lda + ka + lcol;
          float4 x0 = *(const float4*)s;
          float4 x1 = *(const float4*)(s + 4);
          v8us d;
          d[0]=f2bu(x0.x); d[1]=f2bu(x0.y); d[2]=f2bu(x0.z); d[3]=f2bu(x0.w);
          d[4]=f2bu(x1.x); d[5]=f2bu(x1.y); d[6]=f2bu(x1.z); d[7]=f2bu(x1.w);
          *(v8us*)(As + ch * 8 * BK + lane * 8) = d;
        }
      } else {
        const unsigned short* Ab = (const unsigned short*)Ap;
        for (int ch = wv; ch < TM / 8; ch += 4)
          gl_lds16(Ab + (size_t)(bm + ch * 8 + lrow) * lda + ka + lcol,
                   As + ch * 8 * BK);
      }
    }
    {  // ---- stage B tile (canonical bf16) ----
      const bool useB1 = (KSB == 0) || (k0 < KSB);
      const bf16* Bp = useB1 ? B1 : B2;
      const int kb = useB1 ? k0 : k0 - KSB;
      for (int ch = wv; ch < TN / 8; ch += 4)
        gl_lds16((const unsigned short*)Bp + (size_t)(bn + ch * 8 + lrow) * ldb + kb + lcol,
                 Bs + ch * 8 * BK);
    }
    __syncthreads();
#pragma unroll
    for (int kk = 0; kk < BK; kk += 32) {
      v8bf af[FM], bfr[FN];
#pragma unroll
      for (int i = 0; i < FM; ++i)
        af[i] = *(const v8bf*)(As + (wm0 + i * 16 + mr) * BK + kk + kq);
#pragma unroll
      for (int j = 0; j < FN; ++j)
        bfr[j] = *(const v8bf*)(Bs + (wn0 + j * 16 + mr) * BK + kk + kq);
#pragma unroll
      for (int i = 0; i < FM; ++i)
#pragma unroll
        for (int j = 0; j < FN; ++j)
          acc[i][j] = __builtin_amdgcn_mfma_f32_16x16x32_bf16(af[i], bfr[j],
                                                              acc[i][j], 0, 0, 0);
    }
    __syncthreads();
  }
  const int crow = (lane >> 4) * 4;

  if constexpr (ACT == 5) {
    // intent epilogue: TN=128, WC=1 -> wn0=0, FN=8, FM=1. Thread holds mean col
    // (j<4, cols 0..63) and logstd col (j+4, cols 64..127) in its own acc.
#pragma unroll
    for (int j = 0; j < 4; ++j) {
      const int gcol = bn + j * 16 + mr;  // 0..63
      const float bmn = bias[gcol];
      const float bsd = bias[gcol + 64];
#pragma unroll
      for (int r = 0; r < 4; ++r) {
        const int grow = bm + wm0 + crow + r;
        const float mean = acc[0][j][r] + bmn;
        const float lstd = acc[0][j + 4][r] + bsd;
        ((float*)C)[(size_t)grow * 128 + gcol] = mean;
        ((float*)C)[(size_t)grow * 128 + gcol + 64] = lstd;
        const float sd = fmaxf(__expf(lstd), 0.002f);
        const float iv = mean + pe[(size_t)grow * 64 + gcol] * sd;
        pit[(size_t)grow * 64 + gcol] = iv;
        pitb[(size_t)grow * 512 + gcol] = f2bu(iv);
      }
    }
  } else {
#pragma unroll
    for (int j = 0; j < FN; ++j) {
      const int gcol = bn + wn0 + j * 16 + mr;
      const float bv = bias[gcol];
      float ps = 0.f, pq = 0.f;
#pragma unroll
      for (int i = 0; i < FM; ++i) {
#pragma unroll
        for (int r = 0; r < 4; ++r) {
          const int grow = bm + wm0 + i * 16 + crow + r;
          float v = acc[i][j][r] + bv;
          if (ACT == 1) v = v > 0.f ? v : 0.f;
          if constexpr (QKV) {
            if (gcol < 128) ((bf16*)C)[(size_t)grow * 128 + gcol] = f2b(v);
            else ((bf16*)C2)[(size_t)grow * 64 + (gcol - 128)] = f2b(v);
          } else if constexpr (STATS) {
            const unsigned short d = f2bu(v);
            ((bf16*)C)[(size_t)grow * ldc + gcol] = *(const bf16*)&d;
            const float vr = bu2f(d);
            ps += vr; pq += vr * vr;
          } else {
            cstore<CF>(C, (size_t)grow * ldc + gcol, v);
          }
        }
      }
      if constexpr (STATS) {
        // reduce across the 4 row-quarter lanes (same mr, lane>>4 = 0..3)
        ps += __shfl_xor(ps, 16); ps += __shfl_xor(ps, 32);
        pq += __shfl_xor(pq, 16); pq += __shfl_xor(pq, 32);
        if (lane < 16) {
          const int slot = (gcol << 10) + ((bm >> 6) << 1) + (wv % WR);
          PART[slot] = ps;
          PART[262144 + slot] = pq;
        }
      }
    }
  }
}

// Reduce PART -> BN scale/shift. One block per column, 64 lanes, coalesced float4.
// 1024 slots per column (512 m-blocks x 2 row-waves at TM=64).
__global__ __launch_bounds__(64) void bn_finalize2(
    const float* __restrict__ PART, const float* __restrict__ g,
    const float* __restrict__ b, float* __restrict__ stats) {
  const int col = blockIdx.x;
  const int lane = threadIdx.x;
  const float4* ps = (const float4*)(PART + (col << 10));
  const float4* pq = (const float4*)(PART + 262144 + (col << 10));
  float s = 0.f, q = 0.f;
#pragma unroll
  for (int u = 0; u < 4; ++u) {
    const float4 a = ps[lane * 4 + u];
    const float4 c = pq[lane * 4 + u];
    s += a.x + a.y + a.z + a.w;
    q += c.x + c.y + c.z + c.w;
  }
#pragma unroll
  for (int m = 1; m < 64; m <<= 1) {
    s += __shfl_xor(s, m);
    q += __shfl_xor(q, m);
  }
  if (lane == 0) {
    const float mean = s * (1.f / 32768.f);
    float var = q * (1.f / 32768.f) - mean * mean;
    var = fmaxf(var, 0.f);
    const float sc = g[col] * rsqrtf(var + 1e-5f);
    stats[512 + col] = sc;
    stats[768 + col] = b[col] - mean * sc;
  }
}

// Fused GRU: dual-accumulator gemm (i_n = X @ Win^T, hn = HB @ Whn^T) + GRU math.
// TM=64, TN=128, 4 waves (2 rows x 2 col-halves). Grid (512, 2). K=256, BK=32,
// SINGLE-buffered staging (r9's dbuf+vmcnt regressed; this keeps the r8 loop
// shape but halves the tile: LDS staging 24 KB, epilogue 34.8 KB -> block LDS
// ~36 KB -> 4 blocks/CU (VGPR=128 also caps at 4) and all 1024 blocks
// co-resident: other blocks' MFMA hides each block's stage-drain barrier.
// Writes Hout fp32 AND HB2 bf16 (strided over G1's own rows; HB2(r,c) overwrites
// G1(r,c) for c in this block's [bn, bn+128) r-preact range -- each element is
// read (prefetched) then written by the SAME thread; z-preacts at c+256 never
// overwritten; other blocks touch disjoint rows/cols -> race-free).
__global__ __launch_bounds__(256) void gru_fused(
    const bf16* __restrict__ X, const bf16* __restrict__ HB,
    const bf16* __restrict__ Win, const bf16* __restrict__ Whn,
    const float* __restrict__ FBp, const bf16* G1, unsigned short* HB2,
    float* __restrict__ Hout) {
  constexpr int BK = 32;
  __shared__ __align__(16) char smem[34816];
  unsigned short* AsX = (unsigned short*)smem;     // 64x32 us = 4 KB
  unsigned short* AsH = AsX + 2048;                // 4 KB
  unsigned short* Bin = AsH + 2048;                // 128x32 us = 8 KB
  unsigned short* Bhn = Bin + 4096;                // 8 KB   (staging total 24 KB)
  float* Ein = (float*)smem;                       // 64*68 fp32 = 17408 B
  float* Ehn = Ein + 64 * 68;                      // 17408 B (epilogue total 34816)

  const int tid = threadIdx.x;
  const int wv = tid >> 6;
  const int lane = tid & 63;
  const int w = xcd_swz();
  const int bm = (w / gridDim.y) * 64;
  const int bn = (w % gridDim.y) * 128;
  const int wm0 = (wv & 1) * 32;
  const int wn0 = (wv >> 1) * 64;

  v4f ain[2][4], ahn[2][4];
  const v4f vzero = {0.f, 0.f, 0.f, 0.f};
  for (int i = 0; i < 2; ++i)
    for (int j = 0; j < 4; ++j) { ain[i][j] = vzero; ahn[i][j] = vzero; }

  const int lrow2 = lane >> 2;       // 0..15: row within 16-row chunk (BK=32)
  const int lcol2 = (lane & 3) * 8;  // 0,8,16,24
  const int mr = lane & 15;
  const int kq = (lane >> 4) * 8;

  for (int k0 = 0; k0 < 256; k0 += BK) {
    {  // A tiles: 64 rows = 4 chunks of 16; wave wv takes chunk wv
      const size_t aoff = (size_t)(bm + wv * 16 + lrow2) * 256 + k0 + lcol2;
      gl_lds16((const unsigned short*)X + aoff, AsX + wv * 512);
      gl_lds16((const unsigned short*)HB + aoff, AsH + wv * 512);
    }
    for (int c = wv; c < 8; c += 4) {  // B tiles: 128 rows = 8 chunks
      const size_t boff = (size_t)(bn + c * 16 + lrow2) * 256 + k0 + lcol2;
      gl_lds16((const unsigned short*)Win + boff, Bin + c * 512);
      gl_lds16((const unsigned short*)Whn + boff, Bhn + c * 512);
    }
    __syncthreads();
    {
      v8bf ax[2], ah[2], bi[4], bh[4];
#pragma unroll
      for (int i = 0; i < 2; ++i) {
        ax[i] = *(const v8bf*)(AsX + (wm0 + i * 16 + mr) * BK + kq);
        ah[i] = *(const v8bf*)(AsH + (wm0 + i * 16 + mr) * BK + kq);
      }
#pragma unroll
      for (int j = 0; j < 4; ++j) {
        bi[j] = *(const v8bf*)(Bin + (wn0 + j * 16 + mr) * BK + kq);
        bh[j] = *(const v8bf*)(Bhn + (wn0 + j * 16 + mr) * BK + kq);
      }
#pragma unroll
      for (int i = 0; i < 2; ++i)
#pragma unroll
        for (int j = 0; j < 4; ++j) {
          ain[i][j] = __builtin_amdgcn_mfma_f32_16x16x32_bf16(ax[i], bi[j],
                                                              ain[i][j], 0, 0, 0);
          ahn[i][j] = __builtin_amdgcn_mfma_f32_16x16x32_bf16(ah[i], bh[j],
                                                              ahn[i][j], 0, 0, 0);
        }
    }
    __syncthreads();
  }

  const int crow = (lane >> 4) * 4;
  const int myhalf = wn0 >> 6;
  const int c4 = (tid & 15) * 4;
#pragma unroll
  for (int h = 0; h < 2; ++h) {
    // ---- batched prefetch: 12 independent loads, no stores in between ----
    ushort4 r4a[4], z4a[4], hp4a[4];
#pragma unroll
    for (int it = 0; it < 4; ++it) {
      const int grow = bm + (tid >> 4) + it * 16;
      const int gcol = bn + h * 64 + c4;
      const unsigned short* g1p = (const unsigned short*)G1 + (size_t)grow * 512 + gcol;
      r4a[it] = *(const ushort4*)g1p;
      z4a[it] = *(const ushort4*)(g1p + 256);
      hp4a[it] = *(const ushort4*)((const unsigned short*)HB + (size_t)grow * 256 + gcol);
    }
    __syncthreads();
    if (myhalf == h) {
#pragma unroll
      for (int i = 0; i < 2; ++i)
#pragma unroll
        for (int j = 0; j < 4; ++j)
#pragma unroll
          for (int r = 0; r < 4; ++r) {
            const int idx = (wm0 + i * 16 + crow + r) * 68 + j * 16 + mr;
            Ein[idx] = ain[i][j][r];
            Ehn[idx] = ahn[i][j][r];
          }
    }
    __syncthreads();
#pragma unroll
    for (int it = 0; it < 4; ++it) {
      const int row = (tid >> 4) + it * 16;
      const int grow = bm + row;
      const int gcol = bn + h * 64 + c4;
      const float4 ei = *(const float4*)(Ein + row * 68 + c4);
      const float4 eh = *(const float4*)(Ehn + row * 68 + c4);
      const float4 bin4 = *(const float4*)(FBp + 768 + gcol);
      const float4 bhn4 = *(const float4*)(FBp + 1024 + gcol);
      const float rv[4] = {bu2f(r4a[it].x), bu2f(r4a[it].y), bu2f(r4a[it].z), bu2f(r4a[it].w)};
      const float zv[4] = {bu2f(z4a[it].x), bu2f(z4a[it].y), bu2f(z4a[it].z), bu2f(z4a[it].w)};
      const float hpv[4] = {bu2f(hp4a[it].x), bu2f(hp4a[it].y), bu2f(hp4a[it].z), bu2f(hp4a[it].w)};
      const float eiv[4] = {ei.x, ei.y, ei.z, ei.w};
      const float ehv[4] = {eh.x, eh.y, eh.z, eh.w};
      const float biv[4] = {bin4.x, bin4.y, bin4.z, bin4.w};
      const float bhv[4] = {bhn4.x, bhn4.y, bhn4.z, bhn4.w};
      float vo[4];
#pragma unroll
      for (int u = 0; u < 4; ++u) {
        float rr = fsig(rv[u]);
        float zz = fsig(zv[u]);
        float nn = ftanh(eiv[u] + biv[u] + rr * (ehv[u] + bhv[u]));
        vo[u] = (1.f - zz) * nn + zz * hpv[u];
      }
      *(float4*)(Hout + (size_t)grow * 256 + gcol) =
          make_float4(vo[0], vo[1], vo[2], vo[3]);
      ushort4 hb2;
      hb2.x = f2bu(vo[0]); hb2.y = f2bu(vo[1]);
      hb2.z = f2bu(vo[2]); hb2.w = f2bu(vo[3]);
      *(ushort4*)(HB2 + (size_t)grow * 512 + gcol) = hb2;  // strided over dead G1
    }
  }
}

// Canonicalize (fp32 in): weights -> bf16 blob WF, biases -> fp32 blob FB; zero BN stats.
// WF element map: fc1_w@0[65536] w_ih@65536[196608] w_hh@262144[196608]
//   W1P@458752[81920 (256x320, in1_w padded 288->320)] in2_w@540672[32768]
//   (legacy gap 573440..602112 zeroed) fc2_w@602112[10240]
//   WQKV@612352[61440 = 192x320: rows 0..127 = [wq;wk] cols<64 else 0;
//   rows 128..191 = wv]
// FB float map: fc1_b@0[256] BRZ@256[512] BIN@768[256] BHN@1024[256]
//   in1_b@1280[256] in2_b@1536[128] BQK@1664[128] wv_b@1792[64] fc2_b@1856[32]
//   bn_g@1888[256] bn_b@2144[256] (gap) stats@2560[1024, zeroed]
__global__ void conv_all(
    const float* fc1_w, const float* w_ih, const float* w_hh, const float* in1_w,
    const float* in2_w, const float* wq_w, const float* wk_w, const float* wv_w,
    const float* fc2_w, const float* fc1_b, const float* b_ih, const float* b_hh,
    const float* in1_b, const float* in2_b, const float* wq_b, const float* wk_b,
    const float* wv_b, const float* fc2_b, const float* bn_g, const float* bn_b,
    bf16* __restrict__ WF, float* __restrict__ FB) {
  int idx = blockIdx.x * 256 + threadIdx.x;
  if (idx < 673792) {
    float v;
    if (idx < 65536) v = fc1_w[idx];
    else if (idx < 262144) v = w_ih[idx - 65536];
    else if (idx < 458752) v = w_hh[idx - 262144];
    else if (idx < 540672) {
      int j = idx - 458752, r = j / 320, c = j % 320;
      v = (c < 288) ? in1_w[r * 288 + c] : 0.f;
    } else if (idx < 573440) v = in2_w[idx - 540672];
    else if (idx < 602112) {
      v = 0.f;  // legacy region, dead
    } else if (idx < 612352) v = fc2_w[idx - 602112];
    else {  // WQKV 192x320
      int j = idx - 612352, r = j / 320, c = j % 320;
      if (r < 128) v = (c < 64) ? (r < 64 ? wq_w[r * 64 + c]
                                          : wk_w[(r - 64) * 64 + c]) : 0.f;
      else v = wv_w[(size_t)(r - 128) * 320 + c];
    }
    WF[idx] = f2b(v);
  } else if (idx < 677376) {
    int j = idx - 673792;  // 0..3583
    float v;
    if (j < 256) v = fc1_b[j];
    else if (j < 768) v = b_ih[j - 256] + b_hh[j - 256];
    else if (j < 1024) v = b_ih[512 + j - 768];
    else if (j < 1280) v = b_hh[512 + j - 1024];
    else if (j < 1536) v = in1_b[j - 1280];
    else if (j < 1664) v = in2_b[j - 1536];
    else if (j < 1792) { int c = j - 1664; v = (c < 64) ? wq_b[c] : wk_b[c - 64]; }
    else if (j < 1856) v = wv_b[j - 1792];
    else if (j < 1888) v = fc2_b[j - 1856];
    else if (j < 2144) v = bn_g[j - 1888];
    else if (j < 2400) v = bn_b[j - 2144];
    else v = 0.f;  // gap + stats region zeroed
    FB[j] = v;
  }
}

// One launch: hidden->HB (bf16), inputs->XB (bf16), last_actions->LAP ([la|0] bf16).
__global__ void pack_all(const float* __restrict__ h, bf16* __restrict__ hb,
                         const float* __restrict__ x, bf16* __restrict__ xb,
                         const float* __restrict__ la, bf16* __restrict__ lap) {
  const int bid = blockIdx.x;
  if (bid < 8192) {
    const float* s = bid < 4096 ? h : x;
    bf16* d = bid < 4096 ? hb : xb;
    const int i = (bid & 4095) * 256 + threadIdx.x;
    const float4 x0 = ((const float4*)s)[i * 2];
    const float4 x1 = ((const float4*)s)[i * 2 + 1];
    v8us o;
    o[0]=f2bu(x0.x); o[1]=f2bu(x0.y); o[2]=f2bu(x0.z); o[3]=f2bu(x0.w);
    o[4]=f2bu(x1.x); o[5]=f2bu(x1.y); o[6]=f2bu(x1.z); o[7]=f2bu(x1.w);
    ((v8us*)d)[i] = o;
  } else {
    const int i = (bid - 8192) * 256 + threadIdx.x;  // < 262144 (BN_*64/8)
    const int row = i >> 3, cg = i & 7;
    v8us o;
    if (cg < 4) {
      const float4 a = *(const float4*)(la + (size_t)row * 32 + cg * 8);
      const float4 b = *(const float4*)(la + (size_t)row * 32 + cg * 8 + 4);
      o[0]=f2bu(a.x); o[1]=f2bu(a.y); o[2]=f2bu(a.z); o[3]=f2bu(a.w);
      o[4]=f2bu(b.x); o[5]=f2bu(b.y); o[6]=f2bu(b.z); o[7]=f2bu(b.w);
    } else {
      for (int u = 0; u < 8; ++u) o[u] = 0;
    }
    ((v8us*)lap)[i] = o;
  }
}

// 4 heads per block (one per wave), vectorized loads.
__global__ __launch_bounds__(256) void attn(const bf16* __restrict__ QK,
                                            const bf16* __restrict__ Vv,
                                            bf16* __restrict__ comb) {
  __shared__ float q[4][8][65], k[4][8][65], v[4][8][65];
  __shared__ float al[4][8][8];
  const int wv = threadIdx.x >> 6, t = threadIdx.x & 63;
  const int b = blockIdx.x * 4 + wv;
  const size_t rb = (size_t)b * 8;
  const unsigned short* qkb = (const unsigned short*)QK + rb * 128;
#pragma unroll
  for (int p = 0; p < 2; ++p) {
    const int e = t * 8 + p * 512;
    const int row = e >> 7, col = e & 127;
    v8us d = *(const v8us*)(qkb + row * 128 + col);
    if (col < 64) {
#pragma unroll
      for (int u = 0; u < 8; ++u) q[wv][row][col + u] = bu2f(d[u]);
    } else {
#pragma unroll
      for (int u = 0; u < 8; ++u) k[wv][row][col - 64 + u] = bu2f(d[u]);
    }
  }
  {
    const int e = t * 8;
    const int row = e >> 6, col = e & 63;
    v8us d = *(const v8us*)((const unsigned short*)Vv + rb * 64 + row * 64 + col);
#pragma unroll
    for (int u = 0; u < 8; ++u) v[wv][row][col + u] = bu2f(d[u]);
  }
  __syncthreads();
  const int i = t >> 3, j = t & 7;
  float s = 0.f;
#pragma unroll
  for (int a = 0; a < 64; ++a) s += q[wv][i][a] * k[wv][j][a];
  s *= 0.125f;
  if (i == j) s = -1e9f;
  float m = s;
  m = fmaxf(m, __shfl_xor(m, 1, 8));
  m = fmaxf(m, __shfl_xor(m, 2, 8));
  m = fmaxf(m, __shfl_xor(m, 4, 8));
  float e = __expf(s - m);
  float sum = e;
  sum += __shfl_xor(sum, 1, 8);
  sum += __shfl_xor(sum, 2, 8);
  sum += __shfl_xor(sum, 4, 8);
  al[wv][i][j] = e / sum;
  __syncthreads();
  const int a0 = (t & 7) * 8;
  v8us o8;
#pragma unroll
  for (int u = 0; u < 8; ++u) {
    float o = 0.f;
#pragma unroll
    for (int jj = 0; jj < 8; ++jj) o += al[wv][i][jj] * v[wv][jj][a0 + u];
    o8[u] = f2bu(o);
  }
  *(v8us*)((unsigned short*)comb + (rb + i) * 64 + a0) = o8;
}

extern "C" void kernel_launch(void* const* d_in, const int* in_sizes, int n_in,
                              void* d_out, int out_size, void* d_ws, size_t ws_size,
                              hipStream_t stream) {
  (void)in_sizes; (void)n_in; (void)out_size; (void)ws_size;
  const float* inputs = (const float*)d_in[0];
  const float* last_actions = (const float*)d_in[1];
  const float* hidden = (const float*)d_in[2];
  const float* eps = (const float*)d_in[3];

  // d_out is FP32 (reference output dtype)
  float* out = (float*)d_out;
  float* out_lq = out;             // 32768x32 (fc2, written LAST)
  float* out_h = out + 1048576;    // 32768x256
  float* out_it = out + 9437184;   // 32768x64
  float* out_ie = out + 11534336;  // 32768x128

  // HB = bf16(hidden), scratch in the out_ie region (last read: gru_fused; in2
  // writes out_ie after).
  bf16* HB = (bf16*)(out + 11534336);  // 16 MiB as bf16 (32768x256)
  // XB = bf16(inputs), scratch in the out_h region (consumed by fc1 before gru).
  bf16* XB = (bf16*)(out + 1048576);
  // LAP lives in the out_lq region (4 MiB, written only by fc2 at the end).
  bf16* LAP = (bf16*)out_lq;
  // PART: BN-stat partials (4 MiB) in the out_it region (consumed by bn_finalize2
  // before the in2 gemm writes out_it=intent).
  float* PART = out + 9437184;

  // ---- workspace ----
  char* ws = (char*)d_ws;
  bf16* X    = (bf16*)(ws + 0);            // 16 MiB (fc1 -> gru_fused)
  bf16* G1   = (bf16*)(ws + 16777216);     // 32 MiB (G1 gemm -> gru_fused)
  // HB2: bf16 h, STRIDED over G1's rows: elem (r,c) at G1 base + r*512 + c (c<256)
  unsigned short* HB2 = (unsigned short*)(ws + 16777216);
  // ITB: bf16 intent, strided into G1's dead odd halves: (r,c) at r*512 + 256 + c
  unsigned short* ITB = (unsigned short*)(ws + 16777216) + 256;
  bf16* Z1   = (bf16*)(ws + 0);            // 16 MiB over dead X (z1 -> in2)
  bf16* QK   = (bf16*)(ws + 0);            // 8 MiB over dead Z1
  bf16* V    = (bf16*)(ws + 8388608);      // 4 MiB over dead Z1
  bf16* COMB = (bf16*)(ws + 12582912);     // 4 MiB over dead Z1
  float* FB  = (float*)(ws + 50331648);    // 3584 floats @ 48 MiB mark
  bf16*  WF  = (bf16*)(ws + 50348032);     // 673792 bf16
  float* stats = FB + 2560;

  conv_all<<<2646, 256, 0, stream>>>(
      (const float*)d_in[4], (const float*)d_in[6], (const float*)d_in[7],
      (const float*)d_in[10], (const float*)d_in[14], (const float*)d_in[16],
      (const float*)d_in[18], (const float*)d_in[20], (const float*)d_in[22],
      (const float*)d_in[5], (const float*)d_in[8], (const float*)d_in[9],
      (const float*)d_in[11], (const float*)d_in[15], (const float*)d_in[17],
      (const float*)d_in[19], (const float*)d_in[21], (const float*)d_in[23],
      (const float*)d_in[12], (const float*)d_in[13], WF, FB);

  pack_all<<<9216, 256, 0, stream>>>(hidden, HB, inputs, XB, last_actions, LAP);

  // x = relu(xb @ fc1_w^T + fc1_b)   [A bf16 -> X bf16]
  gemm_bt<64, 128, 2, 2, 1, 0, 0, 0, 0, 0, 0, 0, 0><<<dim3(512, 2), 256, 0, stream>>>(
      XB, 256, nullptr, 0, WF + 0, nullptr, 256, FB + 0, X, 256, 256,
      nullptr, nullptr, nullptr, nullptr, nullptr, nullptr, nullptr);
  // G1 = [x | hb] @ [w_ih_rz | w_hh_rz]^T + (b_ih_rz + b_hh_rz)   -> bf16
  gemm_bt<64, 128, 2, 2, 0, 0, 0, 256, 256, 0, 0, 0, 0><<<dim3(512, 4), 256, 0, stream>>>(
      X, 256, HB, 256, WF + 65536, WF + 262144, 256, FB + 256, G1, 512, 512,
      nullptr, nullptr, nullptr, nullptr, nullptr, nullptr, nullptr);
  // out_h (fp32) + HB2 (bf16 strided) = fused GRU (BK=32, 4 blocks/CU)
  gru_fused<<<dim3(512, 2), 256, 0, stream>>>(
      X, HB, WF + 65536 + 512 * 256, WF + 262144 + 512 * 256, FB, G1, HB2, out_h);

  // z1 = [h(bf16) | la_pad(bf16)] @ W1P^T + in1_b (K=320) -> Z1 bf16 + BN partials
  gemm_bt<64, 128, 2, 2, 0, 0, 0, 256, 0, 0, 0, 1, 0><<<dim3(512, 2), 256, 0, stream>>>(
      HB2, 512, LAP, 64, WF + 458752, nullptr, 320, FB + 1280, Z1, 256, 320,
      nullptr, nullptr, PART, nullptr, nullptr, nullptr, nullptr);
  bn_finalize2<<<256, 64, 0, stream>>>(PART, FB + 1888, FB + 2144, stats);
  // intent_embed + intent + ITB in ONE gemm: leaky(bn(z1)) @ in2_w^T + in2_b,
  // epilogue computes intent = mean + eps*max(exp(lstd),2e-3)  [ACT=5, WR=4/WC=1]
  gemm_bt<64, 128, 4, 1, 5, 0, 0, 0, 0, 1, 1, 0, 0><<<dim3(512, 1), 256, 0, stream>>>(
      Z1, 256, nullptr, 0, WF + 540672, nullptr, 256, FB + 1536, out_ie, 128, 256,
      stats + 512, stats + 768, nullptr, eps, out_it, ITB, nullptr);
  // q|k|v in ONE gemm: [intent(bf16) | h(bf16)] @ [wq_pad;wk_pad;wv]^T (K=320,
  // N=192); epilogue routes cols<128 -> QK, cols>=128 -> V.
  gemm_bt<64, 192, 2, 2, 0, 0, 0, 64, 0, 0, 0, 0, 1><<<dim3(512, 1), 256, 0, stream>>>(
      ITB, 512, HB2, 512, WF + 612352, nullptr, 320, FB + 1664, QK, 128, 320,
      nullptr, nullptr, nullptr, nullptr, nullptr, nullptr, V);
  attn<<<1024, 256, 0, stream>>>(QK, V, COMB);
  // local_Q (fp32) = [h(bf16) | combined(bf16)] @ fc2^T   (K=320)
  gemm_bt<64, 32, 4, 1, 0, 0, 0, 256, 0, 1, 0, 0, 0><<<dim3(512, 1), 256, 0, stream>>>(
      HB2, 512, COMB, 64, WF + 602112, nullptr, 320, FB + 1856, out_lq, 32, 320,
      nullptr, nullptr, nullptr, nullptr, nullptr, nullptr, nullptr);
}

// Round 13
// 308.321 us; speedup vs baseline: 1.2485x; 1.0212x over previous
//
#include <hip/hip_runtime.h>
#include <hip/hip_bf16.h>

// Problem dims (fixed): B*N=32768, IN=256, H=256, I=64, A=64, NA=32, NH=256
#define BN_ 32768

using bf16 = __hip_bfloat16;
typedef __bf16 v8bf __attribute__((ext_vector_type(8)));
typedef unsigned short v8us __attribute__((ext_vector_type(8)));
typedef float v4f __attribute__((ext_vector_type(4)));

__device__ __forceinline__ float b2f(bf16 x) { return __bfloat162float(x); }
__device__ __forceinline__ bf16 f2b(float x) { return __float2bfloat16(x); }
__device__ __forceinline__ unsigned short f2bu(float x) {
  bf16 h = __float2bfloat16(x);
  return *reinterpret_cast<unsigned short*>(&h);
}
__device__ __forceinline__ float bu2f(unsigned short u) {
  union { unsigned int i; float f; } x;
  x.i = ((unsigned int)u) << 16;
  return x.f;
}
__device__ __forceinline__ void gl_lds16(const void* g, void* l) {
  __builtin_amdgcn_global_load_lds(
      (const __attribute__((address_space(1))) void*)g,
      (__attribute__((address_space(3))) void*)l, 16, 0, 0);
}
// Fast transcendentals: |err| ~1e-6 relative, exact at +-inf. Fine vs bf16 noise.
__device__ __forceinline__ float fsig(float x) { return 1.f / (1.f + __expf(-x)); }
__device__ __forceinline__ float ftanh(float x) {
  return 1.f - 2.f / (__expf(2.f * x) + 1.f);
}
template <int CF>
__device__ __forceinline__ void cstore(void* C, size_t off, float v) {
  if constexpr (CF) ((float*)C)[off] = v;
  else ((bf16*)C)[off] = f2b(v);
}
// XCD-aware bijective swizzle: same-A blocks adjacent on one XCD L2.
__device__ __forceinline__ int xcd_swz() {
  const int nbx = gridDim.x, nby = gridDim.y;
  const int f = blockIdx.y * nbx + blockIdx.x;
  const int nwg = nbx * nby;
  const int q = nwg >> 3, r = nwg & 7;
  const int xcd = f & 7, l = f >> 3;
  if (r == 0) return xcd * q + l;
  return (xcd < r ? xcd * (q + 1) : r * (q + 1) + (xcd - r) * q) + l;
}

// C = epilogue(Acat @ Bcat^T + bias). CF: 1 -> C fp32, 0 -> C bf16.
// Acat: cols [0,KS) from A1, [KS,K) from A2 (KS=0 -> A1 only). A1M/A2M: 1=fp32, 0=bf16.
// ATF: 1 -> A1 is bf16 and gets v=leaky(v*tsc[col]+tsh[col]) applied during staging.
// ACT: 0 none, 1 relu, 5 intent epilogue (requires TN=128, WC=1, FM=1: thread holds
//      mean col j and logstd col j+4; writes C=out_ie fp32, pit=intent fp32,
//      pitb bf16 stride 512).
// STATS: 1 -> emit per-column partial sum/sumsq (requires TM=64, WR=2:
//   slot = (gcol<<10) + (bm>>6)*2 + rowwave; sums at PART[slot], sumsq at +262144).
// QKV: 1 -> route stores: gcol<128 -> C (ldc=128 bf16), else C2 (ldc=64 bf16).
template <int TM, int TN, int WR, int WC, int ACT, int A1M, int A2M, int KS, int KSB,
          int CF, int ATF, int STATS, int QKV>
__global__ __launch_bounds__(256) void gemm_bt(
    const void* __restrict__ A1, int lda1, const void* __restrict__ A2, int lda2,
    const bf16* __restrict__ B1, const bf16* __restrict__ B2, int ldb,
    const float* __restrict__ bias, void* C, int ldc, int K,
    const float* __restrict__ tsc, const float* __restrict__ tsh,
    float* __restrict__ PART, const float* __restrict__ pe,
    float* __restrict__ pit, unsigned short* __restrict__ pitb, void* C2) {
  constexpr int BK = 64;
  __shared__ __align__(16) unsigned short As[TM * BK];
  __shared__ __align__(16) unsigned short Bs[TN * BK];
  const int tid = threadIdx.x;
  const int wv = tid >> 6;
  const int lane = tid & 63;
  const int w = xcd_swz();
  const int bm = (w / gridDim.y) * TM;
  const int bn = (w % gridDim.y) * TN;

  constexpr int WM = TM / WR, WN = TN / WC;
  constexpr int FM = WM / 16, FN = WN / 16;
  const int wm0 = (wv % WR) * WM;
  const int wn0 = (wv / WR) * WN;

  v4f acc[FM][FN];
  const v4f vzero = {0.f, 0.f, 0.f, 0.f};
  for (int i = 0; i < FM; ++i)
    for (int j = 0; j < FN; ++j) acc[i][j] = vzero;

  const int lrow = lane >> 3;       // row within 8-row chunk
  const int lcol = (lane & 7) * 8;  // col offset, 8 elems per lane
  const int mr = lane & 15;         // MFMA m/n index
  const int kq = (lane >> 4) * 8;   // MFMA k offset

  for (int k0 = 0; k0 < K; k0 += BK) {
    {  // ---- stage A tile ----
      const bool useA1 = (KS == 0) || (k0 < KS);
      const void* Ap = useA1 ? A1 : A2;
      const int lda = useA1 ? lda1 : lda2;
      const int ka = useA1 ? k0 : k0 - KS;
      const bool f32 = useA1 ? (A1M == 1) : (A2M == 1);
      if (ATF && useA1) {
        // bf16 in + per-column BN affine + leaky relu, register-staged
        const unsigned short* Ab = (const unsigned short*)Ap;
        const float4 s0 = *(const float4*)(tsc + ka + lcol);
        const float4 s1 = *(const float4*)(tsc + ka + lcol + 4);
        const float4 h0 = *(const float4*)(tsh + ka + lcol);
        const float4 h1 = *(const float4*)(tsh + ka + lcol + 4);
        const float sc[8] = {s0.x, s0.y, s0.z, s0.w, s1.x, s1.y, s1.z, s1.w};
        const float sh[8] = {h0.x, h0.y, h0.z, h0.w, h1.x, h1.y, h1.z, h1.w};
        for (int ch = wv; ch < TM / 8; ch += 4) {
          const unsigned short* s = Ab + (size_t)(bm + ch * 8 + lrow) * lda + ka + lcol;
          v8us zin = *(const v8us*)s;
          v8us d;
#pragma unroll
          for (int u = 0; u < 8; ++u) {
            float v = bu2f(zin[u]) * sc[u] + sh[u];
            d[u] = f2bu(v > 0.f ? v : 0.01f * v);
          }
          *(v8us*)(As + ch * 8 * BK + lane * 8) = d;
        }
      } else if (f32) {
        const float* Af = (const float*)Ap;
        for (int ch = wv; ch < TM / 8; ch += 4) {
          const float* s = Af + (size_t)(bm + ch * 8 + lrow) * lda + ka + lcol;
          float4 x0 = *(const float4*)s;
          float4 x1 = *(const float4*)(s + 4);
          v8us d;
          d[0]=f2bu(x0.x); d[1]=f2bu(x0.y); d[2]=f2bu(x0.z); d[3]=f2bu(x0.w);
          d[4]=f2bu(x1.x); d[5]=f2bu(x1.y); d[6]=f2bu(x1.z); d[7]=f2bu(x1.w);
          *(v8us*)(As + ch * 8 * BK + lane * 8) = d;
        }
      } else {
        const unsigned short* Ab = (const unsigned short*)Ap;
        for (int ch = wv; ch < TM / 8; ch += 4)
          gl_lds16(Ab + (size_t)(bm + ch * 8 + lrow) * lda + ka + lcol,
                   As + ch * 8 * BK);
      }
    }
    {  // ---- stage B tile (canonical bf16) ----
      const bool useB1 = (KSB == 0) || (k0 < KSB);
      const bf16* Bp = useB1 ? B1 : B2;
      const int kb = useB1 ? k0 : k0 - KSB;
      for (int ch = wv; ch < TN / 8; ch += 4)
        gl_lds16((const unsigned short*)Bp + (size_t)(bn + ch * 8 + lrow) * ldb + kb + lcol,
                 Bs + ch * 8 * BK);
    }
    __syncthreads();
#pragma unroll
    for (int kk = 0; kk < BK; kk += 32) {
      v8bf af[FM], bfr[FN];
#pragma unroll
      for (int i = 0; i < FM; ++i)
        af[i] = *(const v8bf*)(As + (wm0 + i * 16 + mr) * BK + kk + kq);
#pragma unroll
      for (int j = 0; j < FN; ++j)
        bfr[j] = *(const v8bf*)(Bs + (wn0 + j * 16 + mr) * BK + kk + kq);
#pragma unroll
      for (int i = 0; i < FM; ++i)
#pragma unroll
        for (int j = 0; j < FN; ++j)
          acc[i][j] = __builtin_amdgcn_mfma_f32_16x16x32_bf16(af[i], bfr[j],
                                                              acc[i][j], 0, 0, 0);
    }
    __syncthreads();
  }
  const int crow = (lane >> 4) * 4;

  if constexpr (ACT == 5) {
    // intent epilogue: TN=128, WC=1 -> wn0=0, FN=8, FM=1. Thread holds mean col
    // (j<4, cols 0..63) and logstd col (j+4, cols 64..127) in its own acc.
#pragma unroll
    for (int j = 0; j < 4; ++j) {
      const int gcol = bn + j * 16 + mr;  // 0..63
      const float bmn = bias[gcol];
      const float bsd = bias[gcol + 64];
#pragma unroll
      for (int r = 0; r < 4; ++r) {
        const int grow = bm + wm0 + crow + r;
        const float mean = acc[0][j][r] + bmn;
        const float lstd = acc[0][j + 4][r] + bsd;
        ((float*)C)[(size_t)grow * 128 + gcol] = mean;
        ((float*)C)[(size_t)grow * 128 + gcol + 64] = lstd;
        const float sd = fmaxf(__expf(lstd), 0.002f);
        const float iv = mean + pe[(size_t)grow * 64 + gcol] * sd;
        pit[(size_t)grow * 64 + gcol] = iv;
        pitb[(size_t)grow * 512 + gcol] = f2bu(iv);
      }
    }
  } else {
#pragma unroll
    for (int j = 0; j < FN; ++j) {
      const int gcol = bn + wn0 + j * 16 + mr;
      const float bv = bias[gcol];
      float ps = 0.f, pq = 0.f;
#pragma unroll
      for (int i = 0; i < FM; ++i) {
#pragma unroll
        for (int r = 0; r < 4; ++r) {
          const int grow = bm + wm0 + i * 16 + crow + r;
          float v = acc[i][j][r] + bv;
          if (ACT == 1) v = v > 0.f ? v : 0.f;
          if constexpr (QKV) {
            if (gcol < 128) ((bf16*)C)[(size_t)grow * 128 + gcol] = f2b(v);
            else ((bf16*)C2)[(size_t)grow * 64 + (gcol - 128)] = f2b(v);
          } else if constexpr (STATS) {
            const unsigned short d = f2bu(v);
            ((bf16*)C)[(size_t)grow * ldc + gcol] = *(const bf16*)&d;
            const float vr = bu2f(d);
            ps += vr; pq += vr * vr;
          } else {
            cstore<CF>(C, (size_t)grow * ldc + gcol, v);
          }
        }
      }
      if constexpr (STATS) {
        // reduce across the 4 row-quarter lanes (same mr, lane>>4 = 0..3)
        ps += __shfl_xor(ps, 16); ps += __shfl_xor(ps, 32);
        pq += __shfl_xor(pq, 16); pq += __shfl_xor(pq, 32);
        if (lane < 16) {
          const int slot = (gcol << 10) + ((bm >> 6) << 1) + (wv % WR);
          PART[slot] = ps;
          PART[262144 + slot] = pq;
        }
      }
    }
  }
}

// Reduce PART -> BN scale/shift. One block per column, 64 lanes, coalesced float4.
// 1024 slots per column (512 m-blocks x 2 row-waves at TM=64).
__global__ __launch_bounds__(64) void bn_finalize2(
    const float* __restrict__ PART, const float* __restrict__ g,
    const float* __restrict__ b, float* __restrict__ stats) {
  const int col = blockIdx.x;
  const int lane = threadIdx.x;
  const float4* ps = (const float4*)(PART + (col << 10));
  const float4* pq = (const float4*)(PART + 262144 + (col << 10));
  float s = 0.f, q = 0.f;
#pragma unroll
  for (int u = 0; u < 4; ++u) {
    const float4 a = ps[lane * 4 + u];
    const float4 c = pq[lane * 4 + u];
    s += a.x + a.y + a.z + a.w;
    q += c.x + c.y + c.z + c.w;
  }
#pragma unroll
  for (int m = 1; m < 64; m <<= 1) {
    s += __shfl_xor(s, m);
    q += __shfl_xor(q, m);
  }
  if (lane == 0) {
    const float mean = s * (1.f / 32768.f);
    float var = q * (1.f / 32768.f) - mean * mean;
    var = fmaxf(var, 0.f);
    const float sc = g[col] * rsqrtf(var + 1e-5f);
    stats[512 + col] = sc;
    stats[768 + col] = b[col] - mean * sc;
  }
}

// Fused GRU: dual-accumulator gemm (i_n = X @ Win^T, hn = HB @ Whn^T) + GRU math.
// TM=64, TN=128, 4 waves. Grid (512, 2). K=256, BK=32, single-buffered staging;
// LDS ~36 KB -> 4 blocks/CU, all 1024 blocks co-resident.
// T5: s_setprio(1) around the MFMA cluster -- with 4 blocks/CU at staggered
// phases the CU scheduler can favor MFMA-entering waves over load-issuing ones.
// Writes Hout fp32 AND HB2 bf16 (strided over G1's own rows; race-free: each
// overwritten G1 element is read (prefetched) then written by the SAME thread;
// z-preacts at c+256 never overwritten; blocks touch disjoint rows/cols).
__global__ __launch_bounds__(256) void gru_fused(
    const bf16* __restrict__ X, const bf16* __restrict__ HB,
    const bf16* __restrict__ Win, const bf16* __restrict__ Whn,
    const float* __restrict__ FBp, const bf16* G1, unsigned short* HB2,
    float* __restrict__ Hout) {
  constexpr int BK = 32;
  __shared__ __align__(16) char smem[34816];
  unsigned short* AsX = (unsigned short*)smem;     // 64x32 us = 4 KB
  unsigned short* AsH = AsX + 2048;                // 4 KB
  unsigned short* Bin = AsH + 2048;                // 128x32 us = 8 KB
  unsigned short* Bhn = Bin + 4096;                // 8 KB   (staging total 24 KB)
  float* Ein = (float*)smem;                       // 64*68 fp32 = 17408 B
  float* Ehn = Ein + 64 * 68;                      // 17408 B (epilogue total 34816)

  const int tid = threadIdx.x;
  const int wv = tid >> 6;
  const int lane = tid & 63;
  const int w = xcd_swz();
  const int bm = (w / gridDim.y) * 64;
  const int bn = (w % gridDim.y) * 128;
  const int wm0 = (wv & 1) * 32;
  const int wn0 = (wv >> 1) * 64;

  v4f ain[2][4], ahn[2][4];
  const v4f vzero = {0.f, 0.f, 0.f, 0.f};
  for (int i = 0; i < 2; ++i)
    for (int j = 0; j < 4; ++j) { ain[i][j] = vzero; ahn[i][j] = vzero; }

  const int lrow2 = lane >> 2;       // 0..15: row within 16-row chunk (BK=32)
  const int lcol2 = (lane & 3) * 8;  // 0,8,16,24
  const int mr = lane & 15;
  const int kq = (lane >> 4) * 8;

  for (int k0 = 0; k0 < 256; k0 += BK) {
    {  // A tiles: 64 rows = 4 chunks of 16; wave wv takes chunk wv
      const size_t aoff = (size_t)(bm + wv * 16 + lrow2) * 256 + k0 + lcol2;
      gl_lds16((const unsigned short*)X + aoff, AsX + wv * 512);
      gl_lds16((const unsigned short*)HB + aoff, AsH + wv * 512);
    }
    for (int c = wv; c < 8; c += 4) {  // B tiles: 128 rows = 8 chunks
      const size_t boff = (size_t)(bn + c * 16 + lrow2) * 256 + k0 + lcol2;
      gl_lds16((const unsigned short*)Win + boff, Bin + c * 512);
      gl_lds16((const unsigned short*)Whn + boff, Bhn + c * 512);
    }
    __syncthreads();
    {
      v8bf ax[2], ah[2], bi[4], bh[4];
#pragma unroll
      for (int i = 0; i < 2; ++i) {
        ax[i] = *(const v8bf*)(AsX + (wm0 + i * 16 + mr) * BK + kq);
        ah[i] = *(const v8bf*)(AsH + (wm0 + i * 16 + mr) * BK + kq);
      }
#pragma unroll
      for (int j = 0; j < 4; ++j) {
        bi[j] = *(const v8bf*)(Bin + (wn0 + j * 16 + mr) * BK + kq);
        bh[j] = *(const v8bf*)(Bhn + (wn0 + j * 16 + mr) * BK + kq);
      }
      __builtin_amdgcn_s_setprio(1);
#pragma unroll
      for (int i = 0; i < 2; ++i)
#pragma unroll
        for (int j = 0; j < 4; ++j) {
          ain[i][j] = __builtin_amdgcn_mfma_f32_16x16x32_bf16(ax[i], bi[j],
                                                              ain[i][j], 0, 0, 0);
          ahn[i][j] = __builtin_amdgcn_mfma_f32_16x16x32_bf16(ah[i], bh[j],
                                                              ahn[i][j], 0, 0, 0);
        }
      __builtin_amdgcn_s_setprio(0);
    }
    __syncthreads();
  }

  const int crow = (lane >> 4) * 4;
  const int myhalf = wn0 >> 6;
  const int c4 = (tid & 15) * 4;
#pragma unroll
  for (int h = 0; h < 2; ++h) {
    // ---- batched prefetch: 12 independent loads, no stores in between ----
    ushort4 r4a[4], z4a[4], hp4a[4];
#pragma unroll
    for (int it = 0; it < 4; ++it) {
      const int grow = bm + (tid >> 4) + it * 16;
      const int gcol = bn + h * 64 + c4;
      const unsigned short* g1p = (const unsigned short*)G1 + (size_t)grow * 512 + gcol;
      r4a[it] = *(const ushort4*)g1p;
      z4a[it] = *(const ushort4*)(g1p + 256);
      hp4a[it] = *(const ushort4*)((const unsigned short*)HB + (size_t)grow * 256 + gcol);
    }
    __syncthreads();
    if (myhalf == h) {
#pragma unroll
      for (int i = 0; i < 2; ++i)
#pragma unroll
        for (int j = 0; j < 4; ++j)
#pragma unroll
          for (int r = 0; r < 4; ++r) {
            const int idx = (wm0 + i * 16 + crow + r) * 68 + j * 16 + mr;
            Ein[idx] = ain[i][j][r];
            Ehn[idx] = ahn[i][j][r];
          }
    }
    __syncthreads();
#pragma unroll
    for (int it = 0; it < 4; ++it) {
      const int row = (tid >> 4) + it * 16;
      const int grow = bm + row;
      const int gcol = bn + h * 64 + c4;
      const float4 ei = *(const float4*)(Ein + row * 68 + c4);
      const float4 eh = *(const float4*)(Ehn + row * 68 + c4);
      const float4 bin4 = *(const float4*)(FBp + 768 + gcol);
      const float4 bhn4 = *(const float4*)(FBp + 1024 + gcol);
      const float rv[4] = {bu2f(r4a[it].x), bu2f(r4a[it].y), bu2f(r4a[it].z), bu2f(r4a[it].w)};
      const float zv[4] = {bu2f(z4a[it].x), bu2f(z4a[it].y), bu2f(z4a[it].z), bu2f(z4a[it].w)};
      const float hpv[4] = {bu2f(hp4a[it].x), bu2f(hp4a[it].y), bu2f(hp4a[it].z), bu2f(hp4a[it].w)};
      const float eiv[4] = {ei.x, ei.y, ei.z, ei.w};
      const float ehv[4] = {eh.x, eh.y, eh.z, eh.w};
      const float biv[4] = {bin4.x, bin4.y, bin4.z, bin4.w};
      const float bhv[4] = {bhn4.x, bhn4.y, bhn4.z, bhn4.w};
      float vo[4];
#pragma unroll
      for (int u = 0; u < 4; ++u) {
        float rr = fsig(rv[u]);
        float zz = fsig(zv[u]);
        float nn = ftanh(eiv[u] + biv[u] + rr * (ehv[u] + bhv[u]));
        vo[u] = (1.f - zz) * nn + zz * hpv[u];
      }
      *(float4*)(Hout + (size_t)grow * 256 + gcol) =
          make_float4(vo[0], vo[1], vo[2], vo[3]);
      ushort4 hb2;
      hb2.x = f2bu(vo[0]); hb2.y = f2bu(vo[1]);
      hb2.z = f2bu(vo[2]); hb2.w = f2bu(vo[3]);
      *(ushort4*)(HB2 + (size_t)grow * 512 + gcol) = hb2;  // strided over dead G1
    }
  }
}

// Merged canonicalize + input packing (one launch).
// Blocks [0, 2646): weights -> bf16 blob WF, biases -> fp32 blob FB (as before).
// Blocks [2646, 11862): hidden->HB, inputs->XB, last_actions->LAP.
__global__ void conv_pack(
    const float* fc1_w, const float* w_ih, const float* w_hh, const float* in1_w,
    const float* in2_w, const float* wq_w, const float* wk_w, const float* wv_w,
    const float* fc2_w, const float* fc1_b, const float* b_ih, const float* b_hh,
    const float* in1_b, const float* in2_b, const float* wq_b, const float* wk_b,
    const float* wv_b, const float* fc2_b, const float* bn_g, const float* bn_b,
    bf16* __restrict__ WF, float* __restrict__ FB,
    const float* __restrict__ hsrc, bf16* __restrict__ hb,
    const float* __restrict__ xsrc, bf16* __restrict__ xb,
    const float* __restrict__ la, bf16* __restrict__ lap) {
  const int bid0 = blockIdx.x;
  if (bid0 < 2646) {
    int idx = bid0 * 256 + threadIdx.x;
    if (idx < 673792) {
      float v;
      if (idx < 65536) v = fc1_w[idx];
      else if (idx < 262144) v = w_ih[idx - 65536];
      else if (idx < 458752) v = w_hh[idx - 262144];
      else if (idx < 540672) {
        int j = idx - 458752, r = j / 320, c = j % 320;
        v = (c < 288) ? in1_w[r * 288 + c] : 0.f;
      } else if (idx < 573440) v = in2_w[idx - 540672];
      else if (idx < 602112) {
        v = 0.f;  // legacy region, dead
      } else if (idx < 612352) v = fc2_w[idx - 602112];
      else {  // WQKV 192x320
        int j = idx - 612352, r = j / 320, c = j % 320;
        if (r < 128) v = (c < 64) ? (r < 64 ? wq_w[r * 64 + c]
                                            : wk_w[(r - 64) * 64 + c]) : 0.f;
        else v = wv_w[(size_t)(r - 128) * 320 + c];
      }
      WF[idx] = f2b(v);
    } else if (idx < 677376) {
      int j = idx - 673792;  // 0..3583
      float v;
      if (j < 256) v = fc1_b[j];
      else if (j < 768) v = b_ih[j - 256] + b_hh[j - 256];
      else if (j < 1024) v = b_ih[512 + j - 768];
      else if (j < 1280) v = b_hh[512 + j - 1024];
      else if (j < 1536) v = in1_b[j - 1280];
      else if (j < 1664) v = in2_b[j - 1536];
      else if (j < 1792) { int c = j - 1664; v = (c < 64) ? wq_b[c] : wk_b[c - 64]; }
      else if (j < 1856) v = wv_b[j - 1792];
      else if (j < 1888) v = fc2_b[j - 1856];
      else if (j < 2144) v = bn_g[j - 1888];
      else if (j < 2400) v = bn_b[j - 2144];
      else v = 0.f;  // gap + stats region zeroed
      FB[j] = v;
    }
    return;
  }
  const int bid = bid0 - 2646;
  if (bid < 8192) {
    const float* s = bid < 4096 ? hsrc : xsrc;
    bf16* d = bid < 4096 ? hb : xb;
    const int i = (bid & 4095) * 256 + threadIdx.x;
    const float4 x0 = ((const float4*)s)[i * 2];
    const float4 x1 = ((const float4*)s)[i * 2 + 1];
    v8us o;
    o[0]=f2bu(x0.x); o[1]=f2bu(x0.y); o[2]=f2bu(x0.z); o[3]=f2bu(x0.w);
    o[4]=f2bu(x1.x); o[5]=f2bu(x1.y); o[6]=f2bu(x1.z); o[7]=f2bu(x1.w);
    ((v8us*)d)[i] = o;
  } else {
    const int i = (bid - 8192) * 256 + threadIdx.x;  // < 262144 (BN_*64/8)
    const int row = i >> 3, cg = i & 7;
    v8us o;
    if (cg < 4) {
      const float4 a = *(const float4*)(la + (size_t)row * 32 + cg * 8);
      const float4 b = *(const float4*)(la + (size_t)row * 32 + cg * 8 + 4);
      o[0]=f2bu(a.x); o[1]=f2bu(a.y); o[2]=f2bu(a.z); o[3]=f2bu(a.w);
      o[4]=f2bu(b.x); o[5]=f2bu(b.y); o[6]=f2bu(b.z); o[7]=f2bu(b.w);
    } else {
      for (int u = 0; u < 8; ++u) o[u] = 0;
    }
    ((v8us*)lap)[i] = o;
  }
}

// 4 heads per block (one per wave), vectorized loads.
__global__ __launch_bounds__(256) void attn(const bf16* __restrict__ QK,
                                            const bf16* __restrict__ Vv,
                                            bf16* __restrict__ comb) {
  __shared__ float q[4][8][65], k[4][8][65], v[4][8][65];
  __shared__ float al[4][8][8];
  const int wv = threadIdx.x >> 6, t = threadIdx.x & 63;
  const int b = blockIdx.x * 4 + wv;
  const size_t rb = (size_t)b * 8;
  const unsigned short* qkb = (const unsigned short*)QK + rb * 128;
#pragma unroll
  for (int p = 0; p < 2; ++p) {
    const int e = t * 8 + p * 512;
    const int row = e >> 7, col = e & 127;
    v8us d = *(const v8us*)(qkb + row * 128 + col);
    if (col < 64) {
#pragma unroll
      for (int u = 0; u < 8; ++u) q[wv][row][col + u] = bu2f(d[u]);
    } else {
#pragma unroll
      for (int u = 0; u < 8; ++u) k[wv][row][col - 64 + u] = bu2f(d[u]);
    }
  }
  {
    const int e = t * 8;
    const int row = e >> 6, col = e & 63;
    v8us d = *(const v8us*)((const unsigned short*)Vv + rb * 64 + row * 64 + col);
#pragma unroll
    for (int u = 0; u < 8; ++u) v[wv][row][col + u] = bu2f(d[u]);
  }
  __syncthreads();
  const int i = t >> 3, j = t & 7;
  float s = 0.f;
#pragma unroll
  for (int a = 0; a < 64; ++a) s += q[wv][i][a] * k[wv][j][a];
  s *= 0.125f;
  if (i == j) s = -1e9f;
  float m = s;
  m = fmaxf(m, __shfl_xor(m, 1, 8));
  m = fmaxf(m, __shfl_xor(m, 2, 8));
  m = fmaxf(m, __shfl_xor(m, 4, 8));
  float e = __expf(s - m);
  float sum = e;
  sum += __shfl_xor(sum, 1, 8);
  sum += __shfl_xor(sum, 2, 8);
  sum += __shfl_xor(sum, 4, 8);
  al[wv][i][j] = e / sum;
  __syncthreads();
  const int a0 = (t & 7) * 8;
  v8us o8;
#pragma unroll
  for (int u = 0; u < 8; ++u) {
    float o = 0.f;
#pragma unroll
    for (int jj = 0; jj < 8; ++jj) o += al[wv][i][jj] * v[wv][jj][a0 + u];
    o8[u] = f2bu(o);
  }
  *(v8us*)((unsigned short*)comb + (rb + i) * 64 + a0) = o8;
}

extern "C" void kernel_launch(void* const* d_in, const int* in_sizes, int n_in,
                              void* d_out, int out_size, void* d_ws, size_t ws_size,
                              hipStream_t stream) {
  (void)in_sizes; (void)n_in; (void)out_size; (void)ws_size;
  const float* inputs = (const float*)d_in[0];
  const float* last_actions = (const float*)d_in[1];
  const float* hidden = (const float*)d_in[2];
  const float* eps = (const float*)d_in[3];

  // d_out is FP32 (reference output dtype)
  float* out = (float*)d_out;
  float* out_lq = out;             // 32768x32 (fc2, written LAST)
  float* out_h = out + 1048576;    // 32768x256
  float* out_it = out + 9437184;   // 32768x64
  float* out_ie = out + 11534336;  // 32768x128

  // HB = bf16(hidden), scratch in the out_ie region (last read: gru_fused; in2
  // writes out_ie after).
  bf16* HB = (bf16*)(out + 11534336);  // 16 MiB as bf16 (32768x256)
  // XB = bf16(inputs), scratch in the out_h region (consumed by fc1 before gru).
  bf16* XB = (bf16*)(out + 1048576);
  // LAP lives in the out_lq region (4 MiB, written only by fc2 at the end).
  bf16* LAP = (bf16*)out_lq;
  // PART: BN-stat partials (4 MiB) in the out_it region (consumed by bn_finalize2
  // before the in2 gemm writes out_it=intent).
  float* PART = out + 9437184;

  // ---- workspace ----
  char* ws = (char*)d_ws;
  bf16* X    = (bf16*)(ws + 0);            // 16 MiB (fc1 -> gru_fused)
  bf16* G1   = (bf16*)(ws + 16777216);     // 32 MiB (G1 gemm -> gru_fused)
  // HB2: bf16 h, STRIDED over G1's rows: elem (r,c) at G1 base + r*512 + c (c<256)
  unsigned short* HB2 = (unsigned short*)(ws + 16777216);
  // ITB: bf16 intent, strided into G1's dead odd halves: (r,c) at r*512 + 256 + c
  unsigned short* ITB = (unsigned short*)(ws + 16777216) + 256;
  bf16* Z1   = (bf16*)(ws + 0);            // 16 MiB over dead X (z1 -> in2)
  bf16* QK   = (bf16*)(ws + 0);            // 8 MiB over dead Z1
  bf16* V    = (bf16*)(ws + 8388608);      // 4 MiB over dead Z1
  bf16* COMB = (bf16*)(ws + 12582912);     // 4 MiB over dead Z1
  float* FB  = (float*)(ws + 50331648);    // 3584 floats @ 48 MiB mark
  bf16*  WF  = (bf16*)(ws + 50348032);     // 673792 bf16
  float* stats = FB + 2560;

  conv_pack<<<11862, 256, 0, stream>>>(
      (const float*)d_in[4], (const float*)d_in[6], (const float*)d_in[7],
      (const float*)d_in[10], (const float*)d_in[14], (const float*)d_in[16],
      (const float*)d_in[18], (const float*)d_in[20], (const float*)d_in[22],
      (const float*)d_in[5], (const float*)d_in[8], (const float*)d_in[9],
      (const float*)d_in[11], (const float*)d_in[15], (const float*)d_in[17],
      (const float*)d_in[19], (const float*)d_in[21], (const float*)d_in[23],
      (const float*)d_in[12], (const float*)d_in[13], WF, FB,
      hidden, HB, inputs, XB, last_actions, LAP);

  // x = relu(xb @ fc1_w^T + fc1_b)   [A bf16 -> X bf16]
  gemm_bt<64, 128, 2, 2, 1, 0, 0, 0, 0, 0, 0, 0, 0><<<dim3(512, 2), 256, 0, stream>>>(
      XB, 256, nullptr, 0, WF + 0, nullptr, 256, FB + 0, X, 256, 256,
      nullptr, nullptr, nullptr, nullptr, nullptr, nullptr, nullptr);
  // G1 = [x | hb] @ [w_ih_rz | w_hh_rz]^T + (b_ih_rz + b_hh_rz)   -> bf16
  gemm_bt<64, 128, 2, 2, 0, 0, 0, 256, 256, 0, 0, 0, 0><<<dim3(512, 4), 256, 0, stream>>>(
      X, 256, HB, 256, WF + 65536, WF + 262144, 256, FB + 256, G1, 512, 512,
      nullptr, nullptr, nullptr, nullptr, nullptr, nullptr, nullptr);
  // out_h (fp32) + HB2 (bf16 strided) = fused GRU (BK=32, 4 blocks/CU, setprio)
  gru_fused<<<dim3(512, 2), 256, 0, stream>>>(
      X, HB, WF + 65536 + 512 * 256, WF + 262144 + 512 * 256, FB, G1, HB2, out_h);

  // z1 = [h(bf16) | la_pad(bf16)] @ W1P^T + in1_b (K=320) -> Z1 bf16 + BN partials
  gemm_bt<64, 128, 2, 2, 0, 0, 0, 256, 0, 0, 0, 1, 0><<<dim3(512, 2), 256, 0, stream>>>(
      HB2, 512, LAP, 64, WF + 458752, nullptr, 320, FB + 1280, Z1, 256, 320,
      nullptr, nullptr, PART, nullptr, nullptr, nullptr, nullptr);
  bn_finalize2<<<256, 64, 0, stream>>>(PART, FB + 1888, FB + 2144, stats);
  // intent_embed + intent + ITB in ONE gemm: leaky(bn(z1)) @ in2_w^T + in2_b,
  // epilogue computes intent = mean + eps*max(exp(lstd),2e-3)  [ACT=5, WR=4/WC=1]
  gemm_bt<64, 128, 4, 1, 5, 0, 0, 0, 0, 1, 1, 0, 0><<<dim3(512, 1), 256, 0, stream>>>(
      Z1, 256, nullptr, 0, WF + 540672, nullptr, 256, FB + 1536, out_ie, 128, 256,
      stats + 512, stats + 768, nullptr, eps, out_it, ITB, nullptr);
  // q|k|v in ONE gemm: [intent(bf16) | h(bf16)] @ [wq_pad;wk_pad;wv]^T (K=320,
  // N=192); epilogue routes cols<128 -> QK, cols>=128 -> V.
  gemm_bt<64, 192, 2, 2, 0, 0, 0, 64, 0, 0, 0, 0, 1><<<dim3(512, 1), 256, 0, stream>>>(
      ITB, 512, HB2, 512, WF + 612352, nullptr, 320, FB + 1664, QK, 128, 320,
      nullptr, nullptr, nullptr, nullptr, nullptr, nullptr, V);
  attn<<<1024, 256, 0, stream>>>(QK, V, COMB);
  // local_Q (fp32) = [h(bf16) | combined(bf16)] @ fc2^T   (K=320)
  gemm_bt<64, 32, 4, 1, 0, 0, 0, 256, 0, 1, 0, 0, 0><<<dim3(512, 1), 256, 0, stream>>>(
      HB2, 512, COMB, 64, WF + 602112, nullptr, 320, FB + 1856, out_lq, 32, 320,
      nullptr, nullptr, nullptr, nullptr, nullptr, nullptr, nullptr);
}